// Round 1
// 24784.393 us; speedup vs baseline: 1.6259x; 1.6259x over previous
//
#include <hip/hip_runtime.h>
#include <hip/hip_fp16.h>

#define BB 16
#define SS 256
#define DD 512
#define HH 512
#define G4 2048                     // 4*H
#define BLOCK 256
#define WG_PER_B 32
#define GRID (BB * WG_PER_B)        // 512 blocks = 2 per CU (exact co-residency fit)
#define ROWS_PER_WG (G4 / WG_PER_B) // 64
#define ROWS_PER_WAVE (ROWS_PER_WG / 4) // 16

// ---------- helpers ----------

__device__ __forceinline__ float hdot8(uint4 w, float4 ha, float4 hb) {
  union { uint4 u; __half2 h[4]; } cv; cv.u = w;
  float2 f0 = __half22float2(cv.h[0]);
  float2 f1 = __half22float2(cv.h[1]);
  float2 f2 = __half22float2(cv.h[2]);
  float2 f3 = __half22float2(cv.h[3]);
  float acc;
  acc = f0.x * ha.x;
  acc = fmaf(f0.y, ha.y, acc);
  acc = fmaf(f1.x, ha.z, acc);
  acc = fmaf(f1.y, ha.w, acc);
  acc = fmaf(f2.x, hb.x, acc);
  acc = fmaf(f2.y, hb.y, acc);
  acc = fmaf(f3.x, hb.z, acc);
  acc = fmaf(f3.y, hb.w, acc);
  return acc;
}

__device__ __forceinline__ float wave_sum(float x) {
#pragma unroll
  for (int o = 32; o; o >>= 1) x += __shfl_xor(x, o);
  return x;
}

__device__ __forceinline__ float sigm(float x) { return 1.f / (1.f + __expf(-x)); }

__device__ __forceinline__ float tanhx(float x) {
  x = fminf(12.f, fmaxf(-12.f, x));
  float e = __expf(2.f * x);
  return (e - 1.f) / (e + 1.f);
}

// Per-batch inter-workgroup barrier (WG_PER_B WGs), device-scope acq/rel.
__device__ __forceinline__ void batch_barrier(unsigned* cnt, unsigned* gen) {
  __syncthreads();
  if (threadIdx.x == 0) {
    unsigned g = __hip_atomic_load(gen, __ATOMIC_RELAXED, __HIP_MEMORY_SCOPE_AGENT);
    unsigned a = __hip_atomic_fetch_add(cnt, 1u, __ATOMIC_ACQ_REL, __HIP_MEMORY_SCOPE_AGENT);
    if (a == (unsigned)(WG_PER_B - 1)) {
      __hip_atomic_store(cnt, 0u, __ATOMIC_RELAXED, __HIP_MEMORY_SCOPE_AGENT);
      __hip_atomic_store(gen, g + 1u, __ATOMIC_RELEASE, __HIP_MEMORY_SCOPE_AGENT);
    } else {
      while (__hip_atomic_load(gen, __ATOMIC_ACQUIRE, __HIP_MEMORY_SCOPE_AGENT) == g) {
        __builtin_amdgcn_s_sleep(2);
      }
    }
  }
  __syncthreads();
}

// ---------- prep1: fp16 conversions, W1 = wih1+whh1, bias sums, barrier init ----------

__global__ void prep_kernel(const float* __restrict__ whh0,
                            const float* __restrict__ wih1, const float* __restrict__ whh1,
                            const float* __restrict__ bih0, const float* __restrict__ bhh0,
                            const float* __restrict__ bih1, const float* __restrict__ bhh1,
                            unsigned short* __restrict__ Wh0h, unsigned short* __restrict__ W1h,
                            float* __restrict__ bias0, float* __restrict__ bias1,
                            unsigned* __restrict__ bar) {
  const int gid = blockIdx.x * BLOCK + threadIdx.x;
  const int stride = gridDim.x * BLOCK;
  const int N4 = BB * G4 * HH / 4;   // 4,194,304 float4s
  for (int i = gid; i < N4; i += stride) {
    float4 b = ((const float4*)whh0)[i];
    float4 c = ((const float4*)wih1)[i];
    float4 d = ((const float4*)whh1)[i];
    ushort4 rb, rc;
    rb.x = __half_as_ushort(__float2half_rn(b.x));
    rb.y = __half_as_ushort(__float2half_rn(b.y));
    rb.z = __half_as_ushort(__float2half_rn(b.z));
    rb.w = __half_as_ushort(__float2half_rn(b.w));
    rc.x = __half_as_ushort(__float2half_rn(c.x + d.x));
    rc.y = __half_as_ushort(__float2half_rn(c.y + d.y));
    rc.z = __half_as_ushort(__float2half_rn(c.z + d.z));
    rc.w = __half_as_ushort(__float2half_rn(c.w + d.w));
    ((ushort4*)Wh0h)[i] = rb;
    ((ushort4*)W1h)[i]  = rc;
  }
  if (gid < BB * G4 / 4) {
    float4 p = ((const float4*)bih0)[gid];
    float4 q = ((const float4*)bhh0)[gid];
    ((float4*)bias0)[gid] = make_float4(p.x + q.x, p.y + q.y, p.z + q.z, p.w + q.w);
    p = ((const float4*)bih1)[gid];
    q = ((const float4*)bhh1)[gid];
    ((float4*)bias1)[gid] = make_float4(p.x + q.x, p.y + q.y, p.z + q.z, p.w + q.w);
  }
  if (gid < 1024) bar[gid] = 0u;
}

// ---------- prep2: g0x[b][t][row] = sum_k Wih0[b][row][k]*x[b][t][k] + bias0[b][row] ----------

__global__ __launch_bounds__(256) void prep2_gemm(const float* __restrict__ wih0,
                                                  const float* __restrict__ x,
                                                  const float* __restrict__ bias0,
                                                  float* __restrict__ g0x) {
  __shared__ float As[32][132];  // [k][row], +4 pad keeps 16B align & spreads banks
  __shared__ float Xs[32][132];  // [k][t]
  const int bid = blockIdx.x;
  const int b  = bid >> 5;
  const int rt = (bid >> 1) & 15;
  const int tt = bid & 1;
  const int tid = threadIdx.x;
  const int tr = tid & 15;    // row-group
  const int tg = tid >> 4;    // t-group

  float acc[8][8];
#pragma unroll
  for (int i = 0; i < 8; ++i)
#pragma unroll
    for (int j = 0; j < 8; ++j) acc[i][j] = 0.f;

  const float* Wb = wih0 + ((size_t)b * G4 + rt * 128) * DD;
  const float* Xb = x + ((size_t)b * SS + tt * 128) * DD;
  const int lr = tid >> 3;   // 0..31
  const int lc = tid & 7;    // 0..7

  for (int kc = 0; kc < DD; kc += 32) {
#pragma unroll
    for (int p = 0; p < 4; ++p) {
      const int row = lr + p * 32;   // 0..127
      float4 w = *(const float4*)(Wb + (size_t)row * DD + kc + lc * 4);
      As[lc * 4 + 0][row] = w.x; As[lc * 4 + 1][row] = w.y;
      As[lc * 4 + 2][row] = w.z; As[lc * 4 + 3][row] = w.w;
      float4 xv = *(const float4*)(Xb + (size_t)row * DD + kc + lc * 4);
      Xs[lc * 4 + 0][row] = xv.x; Xs[lc * 4 + 1][row] = xv.y;
      Xs[lc * 4 + 2][row] = xv.z; Xs[lc * 4 + 3][row] = xv.w;
    }
    __syncthreads();
#pragma unroll
    for (int k = 0; k < 32; ++k) {
      float4 a0 = *(const float4*)&As[k][tr * 8];
      float4 a1 = *(const float4*)&As[k][tr * 8 + 4];
      float4 b0 = *(const float4*)&Xs[k][tg * 8];
      float4 b1 = *(const float4*)&Xs[k][tg * 8 + 4];
      float av[8] = {a0.x, a0.y, a0.z, a0.w, a1.x, a1.y, a1.z, a1.w};
      float bv[8] = {b0.x, b0.y, b0.z, b0.w, b1.x, b1.y, b1.z, b1.w};
#pragma unroll
      for (int i = 0; i < 8; ++i)
#pragma unroll
        for (int j = 0; j < 8; ++j) acc[i][j] = fmaf(av[i], bv[j], acc[i][j]);
    }
    __syncthreads();
  }

  const int r0g = rt * 128 + tr * 8;
  const int t0g = tt * 128 + tg * 8;
  float bv[8];
#pragma unroll
  for (int i = 0; i < 8; ++i) bv[i] = bias0[b * G4 + r0g + i];
#pragma unroll
  for (int j = 0; j < 8; ++j) {
    float* op = g0x + ((size_t)(b * SS + t0g + j)) * G4 + r0g;
    float4 o0 = make_float4(acc[0][j] + bv[0], acc[1][j] + bv[1], acc[2][j] + bv[2], acc[3][j] + bv[3]);
    float4 o1 = make_float4(acc[4][j] + bv[4], acc[5][j] + bv[5], acc[6][j] + bv[6], acc[7][j] + bv[7]);
    ((float4*)op)[0] = o0;
    ((float4*)op)[1] = o1;
  }
}

// ---------- pointwise: LN x4 gates + activations + c update + LN(c) -> out vec ----------

__device__ __forceinline__ void pointwise(
    int l, const float* __restrict__ gsrc, float* __restrict__ outv,
    float* sh_g, float* sh_c, float (*sh_gam)[HH], float (*sh_bet)[HH],
    float (*sh_redA)[8], float (*sh_redB)[2], float* ywr) {
  const int tid = threadIdx.x;
  const int wave = tid >> 6, lane = tid & 63;

  // stage gates [2048] into LDS
#pragma unroll
  for (int i = tid; i < G4 / 4; i += BLOCK)
    ((float4*)sh_g)[i] = ((const float4*)gsrc)[i];
  __syncthreads();

  float a0[4], a1[4], sv[4], qv[4];
#pragma unroll
  for (int q = 0; q < 4; ++q) {
    a0[q] = sh_g[q * HH + tid];
    a1[q] = sh_g[q * HH + 256 + tid];
    sv[q] = a0[q] + a1[q];
    qv[q] = a0[q] * a0[q] + a1[q] * a1[q];
  }
#pragma unroll
  for (int o = 32; o; o >>= 1) {
#pragma unroll
    for (int q = 0; q < 4; ++q) {
      sv[q] += __shfl_xor(sv[q], o);
      qv[q] += __shfl_xor(qv[q], o);
    }
  }
  if (lane == 0) {
#pragma unroll
    for (int q = 0; q < 4; ++q) { sh_redA[wave][q] = sv[q]; sh_redA[wave][q + 4] = qv[q]; }
  }
  __syncthreads();

  const float inv = 1.f / (float)HH;
  const float gam0 = sh_gam[l][tid], gam1 = sh_gam[l][tid + 256];
  const float bet0 = sh_bet[l][tid], bet1 = sh_bet[l][tid + 256];
  float act0[4], act1[4];
#pragma unroll
  for (int q = 0; q < 4; ++q) {
    float ts = sh_redA[0][q] + sh_redA[1][q] + sh_redA[2][q] + sh_redA[3][q];
    float tq = sh_redA[0][q + 4] + sh_redA[1][q + 4] + sh_redA[2][q + 4] + sh_redA[3][q + 4];
    float m = ts * inv;
    float var = fmaxf(tq * inv - m * m, 0.f);
    float rstd = rsqrtf(var + 1e-5f);
    float n0 = (a0[q] - m) * rstd * gam0 + bet0;
    float n1 = (a1[q] - m) * rstd * gam1 + bet1;
    if (q == 2) { act0[q] = tanhx(n0); act1[q] = tanhx(n1); }
    else        { act0[q] = sigm(n0);  act1[q] = sigm(n1); }
  }
  // c = f*c + i*g  (i=0, f=1, g=2, o=3)
  float c0 = act0[1] * sh_c[tid]       + act0[0] * act0[2];
  float c1 = act1[1] * sh_c[tid + 256] + act1[0] * act1[2];
  sh_c[tid] = c0; sh_c[tid + 256] = c1;
  float cs = c0 + c1, cq = c0 * c0 + c1 * c1;
#pragma unroll
  for (int o = 32; o; o >>= 1) { cs += __shfl_xor(cs, o); cq += __shfl_xor(cq, o); }
  if (lane == 0) { sh_redB[wave][0] = cs; sh_redB[wave][1] = cq; }
  __syncthreads();
  float ts = sh_redB[0][0] + sh_redB[1][0] + sh_redB[2][0] + sh_redB[3][0];
  float tq = sh_redB[0][1] + sh_redB[1][1] + sh_redB[2][1] + sh_redB[3][1];
  float m = ts * inv;
  float rstd = rsqrtf(fmaxf(tq * inv - m * m, 0.f) + 1e-5f);
  float h0 = act0[3] * tanhx((c0 - m) * rstd * gam0 + bet0);
  float h1 = act1[3] * tanhx((c1 - m) * rstd * gam1 + bet1);
  outv[tid] = h0; outv[tid + 256] = h1;
  if (ywr) { ywr[tid] = h0; ywr[tid + 256] = h1; }
  __syncthreads();
}

// ---------- main persistent recurrent kernel ----------
// Weights are loop-invariant: each wave owns 16 rows of Wh0 + 16 rows of W1,
// hoisted into 128 VGPRs before the t-loop (eliminates the per-timestep 64 MB
// weight re-fetch that dominated FETCH_SIZE). 2 blocks/CU -> VGPR budget 256.
// b = blockIdx & 15 keeps all 32 WGs of a batch on one XCD (blockIdx%8 rr),
// making the barrier line + gates buffers XCD-local.

__global__ __launch_bounds__(BLOCK, 2) void lstm_main(
    const unsigned short* __restrict__ Wh0,   // fp16 [B][2048][512]
    const unsigned short* __restrict__ W1,    // fp16 [B][2048][512]
    const float* __restrict__ g0x,            // fp32 [B][256][2048], bias0 folded in
    const float* __restrict__ bias1,
    const float* __restrict__ lnw,
    const float* __restrict__ lnb,
    float* __restrict__ gates0,
    float* __restrict__ gates1,
    unsigned* __restrict__ bar,
    float* __restrict__ y) {
  const int tid = threadIdx.x;
  const int wg = blockIdx.x;
  const int b = wg & 15;     // XCD-local: batch b's 32 WGs all on XCD b%8
  const int wgb = wg >> 4;
  const int wave = tid >> 6;
  const int lane = tid & 63;
  const int row0 = wgb * ROWS_PER_WG + wave * ROWS_PER_WAVE;

  __shared__ __align__(16) float sh_h[HH];
  __shared__ __align__(16) float sh_c[HH];
  __shared__ __align__(16) float sh_in[HH];
  __shared__ __align__(16) float sh_g[G4];
  __shared__ __align__(16) float sh_gam[2][HH];
  __shared__ __align__(16) float sh_bet[2][HH];
  __shared__ float sh_redA[4][8];
  __shared__ float sh_redB[4][2];

  for (int i = tid; i < HH; i += BLOCK) { sh_h[i] = 0.f; sh_c[i] = 0.f; }
  for (int i = tid; i < 2 * HH; i += BLOCK) {
    (&sh_gam[0][0])[i] = lnw[i];
    (&sh_bet[0][0])[i] = lnb[i];
  }

  unsigned* cnt = bar + b * 64;
  unsigned* gen = bar + b * 64 + 32;
  const size_t wbase = (size_t)b * G4 * HH;
  const unsigned short* __restrict__ Wh0b = Wh0 + wbase;
  const unsigned short* __restrict__ W1bp = W1 + wbase;
  const float* bias1b = bias1 + b * G4;
  float* g0b = gates0 + b * G4;
  float* g1b = gates1 + b * G4;

  // ---- hoist loop-invariant weights into registers (16 rows x 16B/lane x 2) ----
  uint4 wv0[ROWS_PER_WAVE], wv1[ROWS_PER_WAVE];
#pragma unroll
  for (int r = 0; r < ROWS_PER_WAVE; ++r) {
    wv0[r] = *(const uint4*)(Wh0b + (size_t)(row0 + r) * HH + lane * 8);
    wv1[r] = *(const uint4*)(W1bp + (size_t)(row0 + r) * HH + lane * 8);
  }
  // loop-invariant bias for phase B (used on lane 0 only)
  float bx1[ROWS_PER_WAVE];
#pragma unroll
  for (int r = 0; r < ROWS_PER_WAVE; ++r) bx1[r] = bias1b[row0 + r];

  __syncthreads();

  for (int t = 0; t < SS; ++t) {
    const float* g0xt = g0x + ((size_t)b * SS + t) * G4;

    float4 ha = *(const float4*)&sh_h[lane * 8];
    float4 hb = *(const float4*)&sh_h[lane * 8 + 4];

    // phase A: gates0 = g0x[t] + Wh0 @ h   (weights already in registers)
    {
      float gx[ROWS_PER_WAVE];
      if (lane == 0) {
#pragma unroll
        for (int r = 0; r < ROWS_PER_WAVE; ++r) gx[r] = g0xt[row0 + r];
      }
#pragma unroll
      for (int r = 0; r < ROWS_PER_WAVE; ++r) {
        float acc = wave_sum(hdot8(wv0[r], ha, hb));
        if (lane == 0) g0b[row0 + r] = acc + gx[r];
      }
    }
    batch_barrier(cnt, gen);

    // layer-0 pointwise -> h0 into sh_in (redundant per WG, deterministic)
    pointwise(0, g0b, sh_in, sh_g, sh_c, sh_gam, sh_bet, sh_redA, sh_redB, nullptr);

    float4 va = *(const float4*)&sh_in[lane * 8];
    float4 vb = *(const float4*)&sh_in[lane * 8 + 4];

    // phase B: gates1 = (wih1+whh1) @ h0 + bias1
#pragma unroll
    for (int r = 0; r < ROWS_PER_WAVE; ++r) {
      float acc = wave_sum(hdot8(wv1[r], va, vb));
      if (lane == 0) g1b[row0 + r] = acc + bx1[r];
    }
    batch_barrier(cnt, gen);

    // layer-1 pointwise -> h into sh_h; leader WG writes y[b][t][:]
    float* ywr = (wgb == 0) ? (y + ((size_t)b * SS + t) * HH) : nullptr;
    pointwise(1, g1b, sh_h, sh_g, sh_c, sh_gam, sh_bet, sh_redA, sh_redB, ywr);
  }
}

// ---------- launch ----------

extern "C" void kernel_launch(void* const* d_in, const int* in_sizes, int n_in,
                              void* d_out, int out_size, void* d_ws, size_t ws_size,
                              hipStream_t stream) {
  const float* x    = (const float*)d_in[0];
  const float* wih0 = (const float*)d_in[1];
  const float* whh0 = (const float*)d_in[2];
  const float* bih0 = (const float*)d_in[3];
  const float* bhh0 = (const float*)d_in[4];
  const float* wih1 = (const float*)d_in[5];
  const float* whh1 = (const float*)d_in[6];
  const float* bih1 = (const float*)d_in[7];
  const float* bhh1 = (const float*)d_in[8];
  const float* lnw  = (const float*)d_in[9];
  const float* lnb  = (const float*)d_in[10];
  float* y = (float*)d_out;

  char* ws = (char*)d_ws;
  const size_t WH = (size_t)BB * G4 * HH * 2;   // 33,554,432 B per fp16 matrix
  const size_t GX = (size_t)BB * SS * G4 * 4;   // 33,554,432 B g0x
  unsigned short* Wh0h = (unsigned short*)(ws);
  unsigned short* W1h  = (unsigned short*)(ws + WH);
  float* g0x   = (float*)(ws + 2 * WH);
  float* bias0 = (float*)(ws + 2 * WH + GX);
  float* bias1 = (float*)(ws + 2 * WH + GX + 131072);
  float* g0    = (float*)(ws + 2 * WH + GX + 2 * 131072);
  float* g1    = (float*)(ws + 2 * WH + GX + 3 * 131072);
  unsigned* bar = (unsigned*)(ws + 2 * WH + GX + 4 * 131072);

  hipLaunchKernelGGL(prep_kernel, dim3(4096), dim3(BLOCK), 0, stream,
                     whh0, wih1, whh1, bih0, bhh0, bih1, bhh1,
                     Wh0h, W1h, bias0, bias1, bar);

  hipLaunchKernelGGL(prep2_gemm, dim3(BB * 32), dim3(256), 0, stream,
                     wih0, x, bias0, g0x);

  void* args[] = { (void*)&Wh0h, (void*)&W1h, (void*)&g0x,
                   (void*)&bias1, (void*)&lnw, (void*)&lnb,
                   (void*)&g0, (void*)&g1, (void*)&bar, (void*)&y };
  hipError_t err = hipLaunchCooperativeKernel(reinterpret_cast<const void*>(&lstm_main),
                                              dim3(GRID), dim3(BLOCK), args, 0, stream);
  if (err != hipSuccess) {
    // fallback: plain launch — grid sized to guaranteed co-residency (2 blocks/CU via launch_bounds)
    hipLaunchKernelGGL(lstm_main, dim3(GRID), dim3(BLOCK), 0, stream,
                       Wh0h, W1h, g0x, bias1, lnw, lnb, g0, g1, bar, y);
  }
}

// Round 2
// 18419.601 us; speedup vs baseline: 2.1877x; 1.3455x over previous
//
#include <hip/hip_runtime.h>
#include <hip/hip_fp16.h>

#define BB 16
#define SS 256
#define DD 512
#define HH 512
#define G4 2048                     // 4*H
#define BLOCK 256
#define WG_PER_B 32
#define GRID (BB * WG_PER_B)        // 512 blocks = 2 per CU (exact co-residency fit)
#define ROWS_PER_WG (G4 / WG_PER_B) // 64
#define ROWS_PER_WAVE (ROWS_PER_WG / 4) // 16

// ---------- helpers ----------

__device__ __forceinline__ float hdot8(uint4 w, float4 ha, float4 hb) {
  union { uint4 u; __half2 h[4]; } cv; cv.u = w;
  float2 f0 = __half22float2(cv.h[0]);
  float2 f1 = __half22float2(cv.h[1]);
  float2 f2 = __half22float2(cv.h[2]);
  float2 f3 = __half22float2(cv.h[3]);
  float acc;
  acc = f0.x * ha.x;
  acc = fmaf(f0.y, ha.y, acc);
  acc = fmaf(f1.x, ha.z, acc);
  acc = fmaf(f1.y, ha.w, acc);
  acc = fmaf(f2.x, hb.x, acc);
  acc = fmaf(f2.y, hb.y, acc);
  acc = fmaf(f3.x, hb.z, acc);
  acc = fmaf(f3.y, hb.w, acc);
  return acc;
}

__device__ __forceinline__ float wave_sum(float x) {
#pragma unroll
  for (int o = 32; o; o >>= 1) x += __shfl_xor(x, o);
  return x;
}

__device__ __forceinline__ float sigm(float x) { return 1.f / (1.f + __expf(-x)); }

__device__ __forceinline__ float tanhx(float x) {
  x = fminf(12.f, fmaxf(-12.f, x));
  float e = __expf(2.f * x);
  return (e - 1.f) / (e + 1.f);
}

// Per-batch inter-workgroup barrier (WG_PER_B WGs), device-scope acq/rel.
__device__ __forceinline__ void batch_barrier(unsigned* cnt, unsigned* gen) {
  __syncthreads();
  if (threadIdx.x == 0) {
    unsigned g = __hip_atomic_load(gen, __ATOMIC_RELAXED, __HIP_MEMORY_SCOPE_AGENT);
    unsigned a = __hip_atomic_fetch_add(cnt, 1u, __ATOMIC_ACQ_REL, __HIP_MEMORY_SCOPE_AGENT);
    if (a == (unsigned)(WG_PER_B - 1)) {
      __hip_atomic_store(cnt, 0u, __ATOMIC_RELAXED, __HIP_MEMORY_SCOPE_AGENT);
      __hip_atomic_store(gen, g + 1u, __ATOMIC_RELEASE, __HIP_MEMORY_SCOPE_AGENT);
    } else {
      while (__hip_atomic_load(gen, __ATOMIC_ACQUIRE, __HIP_MEMORY_SCOPE_AGENT) == g) {
        __builtin_amdgcn_s_sleep(2);
      }
    }
  }
  __syncthreads();
}

// ---------- prep1: fp16 conversions, W1 = wih1+whh1, bias sums, barrier init ----------

__global__ void prep_kernel(const float* __restrict__ whh0,
                            const float* __restrict__ wih1, const float* __restrict__ whh1,
                            const float* __restrict__ bih0, const float* __restrict__ bhh0,
                            const float* __restrict__ bih1, const float* __restrict__ bhh1,
                            unsigned short* __restrict__ Wh0h, unsigned short* __restrict__ W1h,
                            float* __restrict__ bias0, float* __restrict__ bias1,
                            unsigned* __restrict__ bar) {
  const int gid = blockIdx.x * BLOCK + threadIdx.x;
  const int stride = gridDim.x * BLOCK;
  const int N4 = BB * G4 * HH / 4;   // 4,194,304 float4s
  for (int i = gid; i < N4; i += stride) {
    float4 b = ((const float4*)whh0)[i];
    float4 c = ((const float4*)wih1)[i];
    float4 d = ((const float4*)whh1)[i];
    ushort4 rb, rc;
    rb.x = __half_as_ushort(__float2half_rn(b.x));
    rb.y = __half_as_ushort(__float2half_rn(b.y));
    rb.z = __half_as_ushort(__float2half_rn(b.z));
    rb.w = __half_as_ushort(__float2half_rn(b.w));
    rc.x = __half_as_ushort(__float2half_rn(c.x + d.x));
    rc.y = __half_as_ushort(__float2half_rn(c.y + d.y));
    rc.z = __half_as_ushort(__float2half_rn(c.z + d.z));
    rc.w = __half_as_ushort(__float2half_rn(c.w + d.w));
    ((ushort4*)Wh0h)[i] = rb;
    ((ushort4*)W1h)[i]  = rc;
  }
  if (gid < BB * G4 / 4) {
    float4 p = ((const float4*)bih0)[gid];
    float4 q = ((const float4*)bhh0)[gid];
    ((float4*)bias0)[gid] = make_float4(p.x + q.x, p.y + q.y, p.z + q.z, p.w + q.w);
    p = ((const float4*)bih1)[gid];
    q = ((const float4*)bhh1)[gid];
    ((float4*)bias1)[gid] = make_float4(p.x + q.x, p.y + q.y, p.z + q.z, p.w + q.w);
  }
  if (gid < 1024) bar[gid] = 0u;
}

// ---------- prep2: g0x[b][t][row] = sum_k Wih0[b][row][k]*x[b][t][k] + bias0[b][row] ----------

__global__ __launch_bounds__(256) void prep2_gemm(const float* __restrict__ wih0,
                                                  const float* __restrict__ x,
                                                  const float* __restrict__ bias0,
                                                  float* __restrict__ g0x) {
  __shared__ float As[32][132];  // [k][row], +4 pad keeps 16B align & spreads banks
  __shared__ float Xs[32][132];  // [k][t]
  const int bid = blockIdx.x;
  const int b  = bid >> 5;
  const int rt = (bid >> 1) & 15;
  const int tt = bid & 1;
  const int tid = threadIdx.x;
  const int tr = tid & 15;    // row-group
  const int tg = tid >> 4;    // t-group

  float acc[8][8];
#pragma unroll
  for (int i = 0; i < 8; ++i)
#pragma unroll
    for (int j = 0; j < 8; ++j) acc[i][j] = 0.f;

  const float* Wb = wih0 + ((size_t)b * G4 + rt * 128) * DD;
  const float* Xb = x + ((size_t)b * SS + tt * 128) * DD;
  const int lr = tid >> 3;   // 0..31
  const int lc = tid & 7;    // 0..7

  for (int kc = 0; kc < DD; kc += 32) {
#pragma unroll
    for (int p = 0; p < 4; ++p) {
      const int row = lr + p * 32;   // 0..127
      float4 w = *(const float4*)(Wb + (size_t)row * DD + kc + lc * 4);
      As[lc * 4 + 0][row] = w.x; As[lc * 4 + 1][row] = w.y;
      As[lc * 4 + 2][row] = w.z; As[lc * 4 + 3][row] = w.w;
      float4 xv = *(const float4*)(Xb + (size_t)row * DD + kc + lc * 4);
      Xs[lc * 4 + 0][row] = xv.x; Xs[lc * 4 + 1][row] = xv.y;
      Xs[lc * 4 + 2][row] = xv.z; Xs[lc * 4 + 3][row] = xv.w;
    }
    __syncthreads();
#pragma unroll
    for (int k = 0; k < 32; ++k) {
      float4 a0 = *(const float4*)&As[k][tr * 8];
      float4 a1 = *(const float4*)&As[k][tr * 8 + 4];
      float4 b0 = *(const float4*)&Xs[k][tg * 8];
      float4 b1 = *(const float4*)&Xs[k][tg * 8 + 4];
      float av[8] = {a0.x, a0.y, a0.z, a0.w, a1.x, a1.y, a1.z, a1.w};
      float bv[8] = {b0.x, b0.y, b0.z, b0.w, b1.x, b1.y, b1.z, b1.w};
#pragma unroll
      for (int i = 0; i < 8; ++i)
#pragma unroll
        for (int j = 0; j < 8; ++j) acc[i][j] = fmaf(av[i], bv[j], acc[i][j]);
    }
    __syncthreads();
  }

  const int r0g = rt * 128 + tr * 8;
  const int t0g = tt * 128 + tg * 8;
  float bv[8];
#pragma unroll
  for (int i = 0; i < 8; ++i) bv[i] = bias0[b * G4 + r0g + i];
#pragma unroll
  for (int j = 0; j < 8; ++j) {
    float* op = g0x + ((size_t)(b * SS + t0g + j)) * G4 + r0g;
    float4 o0 = make_float4(acc[0][j] + bv[0], acc[1][j] + bv[1], acc[2][j] + bv[2], acc[3][j] + bv[3]);
    float4 o1 = make_float4(acc[4][j] + bv[4], acc[5][j] + bv[5], acc[6][j] + bv[6], acc[7][j] + bv[7]);
    ((float4*)op)[0] = o0;
    ((float4*)op)[1] = o1;
  }
}

// ---------- pointwise: LN x4 gates + activations + c update + LN(c) -> out vec ----------
// gamma/beta live in registers now (each thread only needs its own 4 values per layer).

__device__ __forceinline__ void pointwise(
    const float* __restrict__ gsrc, float* __restrict__ outv,
    float* sh_g, float* sh_c,
    float gam0, float gam1, float bet0, float bet1,
    float (*sh_redA)[8], float (*sh_redB)[2], float* ywr) {
  const int tid = threadIdx.x;
  const int wave = tid >> 6, lane = tid & 63;

  // stage gates [2048] into LDS
#pragma unroll
  for (int i = tid; i < G4 / 4; i += BLOCK)
    ((float4*)sh_g)[i] = ((const float4*)gsrc)[i];
  __syncthreads();

  float a0[4], a1[4], sv[4], qv[4];
#pragma unroll
  for (int q = 0; q < 4; ++q) {
    a0[q] = sh_g[q * HH + tid];
    a1[q] = sh_g[q * HH + 256 + tid];
    sv[q] = a0[q] + a1[q];
    qv[q] = a0[q] * a0[q] + a1[q] * a1[q];
  }
#pragma unroll
  for (int o = 32; o; o >>= 1) {
#pragma unroll
    for (int q = 0; q < 4; ++q) {
      sv[q] += __shfl_xor(sv[q], o);
      qv[q] += __shfl_xor(qv[q], o);
    }
  }
  if (lane == 0) {
#pragma unroll
    for (int q = 0; q < 4; ++q) { sh_redA[wave][q] = sv[q]; sh_redA[wave][q + 4] = qv[q]; }
  }
  __syncthreads();

  const float inv = 1.f / (float)HH;
  float act0[4], act1[4];
#pragma unroll
  for (int q = 0; q < 4; ++q) {
    float ts = sh_redA[0][q] + sh_redA[1][q] + sh_redA[2][q] + sh_redA[3][q];
    float tq = sh_redA[0][q + 4] + sh_redA[1][q + 4] + sh_redA[2][q + 4] + sh_redA[3][q + 4];
    float m = ts * inv;
    float var = fmaxf(tq * inv - m * m, 0.f);
    float rstd = rsqrtf(var + 1e-5f);
    float n0 = (a0[q] - m) * rstd * gam0 + bet0;
    float n1 = (a1[q] - m) * rstd * gam1 + bet1;
    if (q == 2) { act0[q] = tanhx(n0); act1[q] = tanhx(n1); }
    else        { act0[q] = sigm(n0);  act1[q] = sigm(n1); }
  }
  // c = f*c + i*g  (i=0, f=1, g=2, o=3)
  float c0 = act0[1] * sh_c[tid]       + act0[0] * act0[2];
  float c1 = act1[1] * sh_c[tid + 256] + act1[0] * act1[2];
  sh_c[tid] = c0; sh_c[tid + 256] = c1;
  float cs = c0 + c1, cq = c0 * c0 + c1 * c1;
#pragma unroll
  for (int o = 32; o; o >>= 1) { cs += __shfl_xor(cs, o); cq += __shfl_xor(cq, o); }
  if (lane == 0) { sh_redB[wave][0] = cs; sh_redB[wave][1] = cq; }
  __syncthreads();
  float ts = sh_redB[0][0] + sh_redB[1][0] + sh_redB[2][0] + sh_redB[3][0];
  float tq = sh_redB[0][1] + sh_redB[1][1] + sh_redB[2][1] + sh_redB[3][1];
  float m = ts * inv;
  float rstd = rsqrtf(fmaxf(tq * inv - m * m, 0.f) + 1e-5f);
  float h0 = act0[3] * tanhx((c0 - m) * rstd * gam0 + bet0);
  float h1 = act1[3] * tanhx((c1 - m) * rstd * gam1 + bet1);
  outv[tid] = h0; outv[tid + 256] = h1;
  if (ywr) { ywr[tid] = h0; ywr[tid + 256] = h1; }
  __syncthreads();
}

// ---------- main persistent recurrent kernel ----------
// Each wave owns 16 rows of Wh0 + 16 rows of W1 hoisted into 128 VGPRs.
// amdgpu_waves_per_eu(2,2) pins the allocator to the 256-VGPR budget (GRID=512
// can only use 2 blocks/CU anyway) so it cannot rematerialize the weight loads
// inside the t-loop (R1 post-mortem: that remat re-fetched 7.4 GB and was the
// entire critical path). Keep-alive asm makes remat impossible outright.

__global__ __attribute__((amdgpu_waves_per_eu(2, 2))) __launch_bounds__(BLOCK)
void lstm_main(
    const unsigned short* __restrict__ Wh0,   // fp16 [B][2048][512]
    const unsigned short* __restrict__ W1,    // fp16 [B][2048][512]
    const float* __restrict__ g0x,            // fp32 [B][256][2048], bias0 folded in
    const float* __restrict__ bias1,
    const float* __restrict__ lnw,
    const float* __restrict__ lnb,
    float* __restrict__ gates0,
    float* __restrict__ gates1,
    unsigned* __restrict__ bar,
    float* __restrict__ y) {
  const int tid = threadIdx.x;
  const int wg = blockIdx.x;
  const int b = wg & 15;     // XCD-local: batch b's 32 WGs all on XCD b%8
  const int wgb = wg >> 4;
  const int wave = tid >> 6;
  const int lane = tid & 63;
  const int row0 = wgb * ROWS_PER_WG + wave * ROWS_PER_WAVE;

  __shared__ __align__(16) float sh_h[HH];
  __shared__ __align__(16) float sh_c[HH];
  __shared__ __align__(16) float sh_in[HH];
  __shared__ __align__(16) float sh_g[G4];
  __shared__ float sh_redA[4][8];
  __shared__ float sh_redB[4][2];

  for (int i = tid; i < HH; i += BLOCK) { sh_h[i] = 0.f; sh_c[i] = 0.f; }

  // gamma/beta in registers
  const float gam0_l0 = lnw[tid],      gam1_l0 = lnw[tid + 256];
  const float gam0_l1 = lnw[HH + tid], gam1_l1 = lnw[HH + tid + 256];
  const float bet0_l0 = lnb[tid],      bet1_l0 = lnb[tid + 256];
  const float bet0_l1 = lnb[HH + tid], bet1_l1 = lnb[HH + tid + 256];

  unsigned* cnt = bar + b * 64;
  unsigned* gen = bar + b * 64 + 32;
  const size_t wbase = (size_t)b * G4 * HH;
  const unsigned short* __restrict__ Wh0b = Wh0 + wbase;
  const unsigned short* __restrict__ W1bp = W1 + wbase;
  float* g0b = gates0 + b * G4;
  float* g1b = gates1 + b * G4;

  // ---- hoist loop-invariant weights into registers (16 rows x 16B/lane x 2) ----
  uint4 wv0[ROWS_PER_WAVE], wv1[ROWS_PER_WAVE];
#pragma unroll
  for (int r = 0; r < ROWS_PER_WAVE; ++r) {
    wv0[r] = *(const uint4*)(Wh0b + (size_t)(row0 + r) * HH + lane * 8);
    wv1[r] = *(const uint4*)(W1bp + (size_t)(row0 + r) * HH + lane * 8);
  }
  // forbid rematerialization: values are now asm-defined, not reloadable
#pragma unroll
  for (int r = 0; r < ROWS_PER_WAVE; ++r) {
    asm volatile("" : "+v"(wv0[r].x), "+v"(wv0[r].y), "+v"(wv0[r].z), "+v"(wv0[r].w),
                      "+v"(wv1[r].x), "+v"(wv1[r].y), "+v"(wv1[r].z), "+v"(wv1[r].w));
  }

  // loop-invariant bias for phase B: lane l < 16 owns row row0+l (coalesced)
  const float bx = (lane < ROWS_PER_WAVE) ? bias1[b * G4 + row0 + lane] : 0.f;

  __syncthreads();

  for (int t = 0; t < SS; ++t) {
    const float* g0xt = g0x + ((size_t)b * SS + t) * G4;

    float4 ha = *(const float4*)&sh_h[lane * 8];
    float4 hb = *(const float4*)&sh_h[lane * 8 + 4];

    // phase A: gates0 = g0x[t] + Wh0 @ h   (weights in registers)
    {
      float accv[ROWS_PER_WAVE];
#pragma unroll
      for (int r = 0; r < ROWS_PER_WAVE; ++r)
        accv[r] = wave_sum(hdot8(wv0[r], ha, hb));
      float out = 0.f;
#pragma unroll
      for (int r = 0; r < ROWS_PER_WAVE; ++r) if (lane == r) out = accv[r];
      if (lane < ROWS_PER_WAVE)
        g0b[row0 + lane] = out + g0xt[row0 + lane];   // coalesced 16-lane store
    }
    batch_barrier(cnt, gen);

    // layer-0 pointwise -> h0 into sh_in (redundant per WG, deterministic)
    pointwise(g0b, sh_in, sh_g, sh_c, gam0_l0, gam1_l0, bet0_l0, bet1_l0,
              sh_redA, sh_redB, nullptr);

    float4 va = *(const float4*)&sh_in[lane * 8];
    float4 vb = *(const float4*)&sh_in[lane * 8 + 4];

    // phase B: gates1 = (wih1+whh1) @ h0 + bias1
    {
      float accv[ROWS_PER_WAVE];
#pragma unroll
      for (int r = 0; r < ROWS_PER_WAVE; ++r)
        accv[r] = wave_sum(hdot8(wv1[r], va, vb));
      float out = 0.f;
#pragma unroll
      for (int r = 0; r < ROWS_PER_WAVE; ++r) if (lane == r) out = accv[r];
      if (lane < ROWS_PER_WAVE)
        g1b[row0 + lane] = out + bx;                  // coalesced 16-lane store
    }
    batch_barrier(cnt, gen);

    // layer-1 pointwise -> h into sh_h; leader WG writes y[b][t][:]
    float* ywr = (wgb == 0) ? (y + ((size_t)b * SS + t) * HH) : nullptr;
    pointwise(g1b, sh_h, sh_g, sh_c, gam0_l1, gam1_l1, bet0_l1, bet1_l1,
              sh_redA, sh_redB, ywr);
  }
}

// ---------- launch ----------

extern "C" void kernel_launch(void* const* d_in, const int* in_sizes, int n_in,
                              void* d_out, int out_size, void* d_ws, size_t ws_size,
                              hipStream_t stream) {
  const float* x    = (const float*)d_in[0];
  const float* wih0 = (const float*)d_in[1];
  const float* whh0 = (const float*)d_in[2];
  const float* bih0 = (const float*)d_in[3];
  const float* bhh0 = (const float*)d_in[4];
  const float* wih1 = (const float*)d_in[5];
  const float* whh1 = (const float*)d_in[6];
  const float* bih1 = (const float*)d_in[7];
  const float* bhh1 = (const float*)d_in[8];
  const float* lnw  = (const float*)d_in[9];
  const float* lnb  = (const float*)d_in[10];
  float* y = (float*)d_out;

  char* ws = (char*)d_ws;
  const size_t WH = (size_t)BB * G4 * HH * 2;   // 33,554,432 B per fp16 matrix
  const size_t GX = (size_t)BB * SS * G4 * 4;   // 33,554,432 B g0x
  unsigned short* Wh0h = (unsigned short*)(ws);
  unsigned short* W1h  = (unsigned short*)(ws + WH);
  float* g0x   = (float*)(ws + 2 * WH);
  float* bias0 = (float*)(ws + 2 * WH + GX);
  float* bias1 = (float*)(ws + 2 * WH + GX + 131072);
  float* g0    = (float*)(ws + 2 * WH + GX + 2 * 131072);
  float* g1    = (float*)(ws + 2 * WH + GX + 3 * 131072);
  unsigned* bar = (unsigned*)(ws + 2 * WH + GX + 4 * 131072);

  hipLaunchKernelGGL(prep_kernel, dim3(4096), dim3(BLOCK), 0, stream,
                     whh0, wih1, whh1, bih0, bhh0, bih1, bhh1,
                     Wh0h, W1h, bias0, bias1, bar);

  hipLaunchKernelGGL(prep2_gemm, dim3(BB * 32), dim3(256), 0, stream,
                     wih0, x, bias0, g0x);

  void* args[] = { (void*)&Wh0h, (void*)&W1h, (void*)&g0x,
                   (void*)&bias1, (void*)&lnw, (void*)&lnb,
                   (void*)&g0, (void*)&g1, (void*)&bar, (void*)&y };
  hipError_t err = hipLaunchCooperativeKernel(reinterpret_cast<const void*>(&lstm_main),
                                              dim3(GRID), dim3(BLOCK), args, 0, stream);
  if (err != hipSuccess) {
    // fallback: plain launch — grid sized to guaranteed co-residency (2 blocks/CU)
    hipLaunchKernelGGL(lstm_main, dim3(GRID), dim3(BLOCK), 0, stream,
                       Wh0h, W1h, g0x, bias1, lnw, lnb, g0, g1, bar, y);
  }
}

// Round 3
// 13892.358 us; speedup vs baseline: 2.9007x; 1.3259x over previous
//
#include <hip/hip_runtime.h>
#include <hip/hip_fp16.h>

#define BB 16
#define SS 256
#define DD 512
#define HH 512
#define G4 2048                     // 4*H
#define BLOCK 256
#define WG_PER_B 32
#define GRID (BB * WG_PER_B)        // 512 blocks = 2 per CU (exact co-residency fit)
#define ROWS_PER_WG (G4 / WG_PER_B) // 64
#define ROWS_PER_WAVE (ROWS_PER_WG / 4) // 16

// ---------- helpers ----------

__device__ __forceinline__ float hdot8(uint4 w, float4 ha, float4 hb) {
  union { uint4 u; __half2 h[4]; } cv; cv.u = w;
  float2 f0 = __half22float2(cv.h[0]);
  float2 f1 = __half22float2(cv.h[1]);
  float2 f2 = __half22float2(cv.h[2]);
  float2 f3 = __half22float2(cv.h[3]);
  float acc;
  acc = f0.x * ha.x;
  acc = fmaf(f0.y, ha.y, acc);
  acc = fmaf(f1.x, ha.z, acc);
  acc = fmaf(f1.y, ha.w, acc);
  acc = fmaf(f2.x, hb.x, acc);
  acc = fmaf(f2.y, hb.y, acc);
  acc = fmaf(f3.x, hb.z, acc);
  acc = fmaf(f3.y, hb.w, acc);
  return acc;
}

__device__ __forceinline__ float wave_sum(float x) {
#pragma unroll
  for (int o = 32; o; o >>= 1) x += __shfl_xor(x, o);
  return x;
}

__device__ __forceinline__ float sigm(float x) { return 1.f / (1.f + __expf(-x)); }

__device__ __forceinline__ float tanhx(float x) {
  x = fminf(12.f, fmaxf(-12.f, x));
  float e = __expf(2.f * x);
  return (e - 1.f) / (e + 1.f);
}

// Per-batch inter-workgroup barrier (WG_PER_B WGs), device-scope acq/rel.
__device__ __forceinline__ void batch_barrier(unsigned* cnt, unsigned* gen) {
  __syncthreads();
  if (threadIdx.x == 0) {
    unsigned g = __hip_atomic_load(gen, __ATOMIC_RELAXED, __HIP_MEMORY_SCOPE_AGENT);
    unsigned a = __hip_atomic_fetch_add(cnt, 1u, __ATOMIC_ACQ_REL, __HIP_MEMORY_SCOPE_AGENT);
    if (a == (unsigned)(WG_PER_B - 1)) {
      __hip_atomic_store(cnt, 0u, __ATOMIC_RELAXED, __HIP_MEMORY_SCOPE_AGENT);
      __hip_atomic_store(gen, g + 1u, __ATOMIC_RELEASE, __HIP_MEMORY_SCOPE_AGENT);
    } else {
      while (__hip_atomic_load(gen, __ATOMIC_ACQUIRE, __HIP_MEMORY_SCOPE_AGENT) == g) {
        __builtin_amdgcn_s_sleep(2);
      }
    }
  }
  __syncthreads();
}

// ---------- prep1: fp16 conversions, W1 = wih1+whh1, bias sums, barrier init ----------

__global__ void prep_kernel(const float* __restrict__ whh0,
                            const float* __restrict__ wih1, const float* __restrict__ whh1,
                            const float* __restrict__ bih0, const float* __restrict__ bhh0,
                            const float* __restrict__ bih1, const float* __restrict__ bhh1,
                            unsigned short* __restrict__ Wh0h, unsigned short* __restrict__ W1h,
                            float* __restrict__ bias0, float* __restrict__ bias1,
                            unsigned* __restrict__ bar) {
  const int gid = blockIdx.x * BLOCK + threadIdx.x;
  const int stride = gridDim.x * BLOCK;
  const int N4 = BB * G4 * HH / 4;   // 4,194,304 float4s
  for (int i = gid; i < N4; i += stride) {
    float4 b = ((const float4*)whh0)[i];
    float4 c = ((const float4*)wih1)[i];
    float4 d = ((const float4*)whh1)[i];
    ushort4 rb, rc;
    rb.x = __half_as_ushort(__float2half_rn(b.x));
    rb.y = __half_as_ushort(__float2half_rn(b.y));
    rb.z = __half_as_ushort(__float2half_rn(b.z));
    rb.w = __half_as_ushort(__float2half_rn(b.w));
    rc.x = __half_as_ushort(__float2half_rn(c.x + d.x));
    rc.y = __half_as_ushort(__float2half_rn(c.y + d.y));
    rc.z = __half_as_ushort(__float2half_rn(c.z + d.z));
    rc.w = __half_as_ushort(__float2half_rn(c.w + d.w));
    ((ushort4*)Wh0h)[i] = rb;
    ((ushort4*)W1h)[i]  = rc;
  }
  if (gid < BB * G4 / 4) {
    float4 p = ((const float4*)bih0)[gid];
    float4 q = ((const float4*)bhh0)[gid];
    ((float4*)bias0)[gid] = make_float4(p.x + q.x, p.y + q.y, p.z + q.z, p.w + q.w);
    p = ((const float4*)bih1)[gid];
    q = ((const float4*)bhh1)[gid];
    ((float4*)bias1)[gid] = make_float4(p.x + q.x, p.y + q.y, p.z + q.z, p.w + q.w);
  }
  if (gid < 1024) bar[gid] = 0u;
}

// ---------- prep2: g0x[b][t][row] = sum_k Wih0[b][row][k]*x[b][t][k] + bias0[b][row] ----------

__global__ __launch_bounds__(256) void prep2_gemm(const float* __restrict__ wih0,
                                                  const float* __restrict__ x,
                                                  const float* __restrict__ bias0,
                                                  float* __restrict__ g0x) {
  __shared__ float As[32][132];  // [k][row], +4 pad keeps 16B align & spreads banks
  __shared__ float Xs[32][132];  // [k][t]
  const int bid = blockIdx.x;
  const int b  = bid >> 5;
  const int rt = (bid >> 1) & 15;
  const int tt = bid & 1;
  const int tid = threadIdx.x;
  const int tr = tid & 15;    // row-group
  const int tg = tid >> 4;    // t-group

  float acc[8][8];
#pragma unroll
  for (int i = 0; i < 8; ++i)
#pragma unroll
    for (int j = 0; j < 8; ++j) acc[i][j] = 0.f;

  const float* Wb = wih0 + ((size_t)b * G4 + rt * 128) * DD;
  const float* Xb = x + ((size_t)b * SS + tt * 128) * DD;
  const int lr = tid >> 3;   // 0..31
  const int lc = tid & 7;    // 0..7

  for (int kc = 0; kc < DD; kc += 32) {
#pragma unroll
    for (int p = 0; p < 4; ++p) {
      const int row = lr + p * 32;   // 0..127
      float4 w = *(const float4*)(Wb + (size_t)row * DD + kc + lc * 4);
      As[lc * 4 + 0][row] = w.x; As[lc * 4 + 1][row] = w.y;
      As[lc * 4 + 2][row] = w.z; As[lc * 4 + 3][row] = w.w;
      float4 xv = *(const float4*)(Xb + (size_t)row * DD + kc + lc * 4);
      Xs[lc * 4 + 0][row] = xv.x; Xs[lc * 4 + 1][row] = xv.y;
      Xs[lc * 4 + 2][row] = xv.z; Xs[lc * 4 + 3][row] = xv.w;
    }
    __syncthreads();
#pragma unroll
    for (int k = 0; k < 32; ++k) {
      float4 a0 = *(const float4*)&As[k][tr * 8];
      float4 a1 = *(const float4*)&As[k][tr * 8 + 4];
      float4 b0 = *(const float4*)&Xs[k][tg * 8];
      float4 b1 = *(const float4*)&Xs[k][tg * 8 + 4];
      float av[8] = {a0.x, a0.y, a0.z, a0.w, a1.x, a1.y, a1.z, a1.w};
      float bv[8] = {b0.x, b0.y, b0.z, b0.w, b1.x, b1.y, b1.z, b1.w};
#pragma unroll
      for (int i = 0; i < 8; ++i)
#pragma unroll
        for (int j = 0; j < 8; ++j) acc[i][j] = fmaf(av[i], bv[j], acc[i][j]);
    }
    __syncthreads();
  }

  const int r0g = rt * 128 + tr * 8;
  const int t0g = tt * 128 + tg * 8;
  float bv[8];
#pragma unroll
  for (int i = 0; i < 8; ++i) bv[i] = bias0[b * G4 + r0g + i];
#pragma unroll
  for (int j = 0; j < 8; ++j) {
    float* op = g0x + ((size_t)(b * SS + t0g + j)) * G4 + r0g;
    float4 o0 = make_float4(acc[0][j] + bv[0], acc[1][j] + bv[1], acc[2][j] + bv[2], acc[3][j] + bv[3]);
    float4 o1 = make_float4(acc[4][j] + bv[4], acc[5][j] + bv[5], acc[6][j] + bv[6], acc[7][j] + bv[7]);
    ((float4*)op)[0] = o0;
    ((float4*)op)[1] = o1;
  }
}

// ---------- pointwise: LN x4 gates + activations + c update + LN(c) -> out vec ----------
// Gates read DIRECTLY from global (coalesced, L2-hit, each value read once —
// the old LDS staging was a pure extra round-trip). gamma/beta in registers.

__device__ __forceinline__ void pointwise(
    const float* __restrict__ gsrc, float* __restrict__ outv,
    float* sh_c,
    float gam0, float gam1, float bet0, float bet1,
    float (*sh_redA)[8], float (*sh_redB)[2], float* ywr) {
  const int tid = threadIdx.x;
  const int wave = tid >> 6, lane = tid & 63;

  float a0[4], a1[4], sv[4], qv[4];
#pragma unroll
  for (int q = 0; q < 4; ++q) {
    a0[q] = gsrc[q * HH + tid];
    a1[q] = gsrc[q * HH + 256 + tid];
    sv[q] = a0[q] + a1[q];
    qv[q] = a0[q] * a0[q] + a1[q] * a1[q];
  }
#pragma unroll
  for (int o = 32; o; o >>= 1) {
#pragma unroll
    for (int q = 0; q < 4; ++q) {
      sv[q] += __shfl_xor(sv[q], o);
      qv[q] += __shfl_xor(qv[q], o);
    }
  }
  if (lane == 0) {
#pragma unroll
    for (int q = 0; q < 4; ++q) { sh_redA[wave][q] = sv[q]; sh_redA[wave][q + 4] = qv[q]; }
  }
  __syncthreads();

  const float inv = 1.f / (float)HH;
  float act0[4], act1[4];
#pragma unroll
  for (int q = 0; q < 4; ++q) {
    float ts = sh_redA[0][q] + sh_redA[1][q] + sh_redA[2][q] + sh_redA[3][q];
    float tq = sh_redA[0][q + 4] + sh_redA[1][q + 4] + sh_redA[2][q + 4] + sh_redA[3][q + 4];
    float m = ts * inv;
    float var = fmaxf(tq * inv - m * m, 0.f);
    float rstd = rsqrtf(var + 1e-5f);
    float n0 = (a0[q] - m) * rstd * gam0 + bet0;
    float n1 = (a1[q] - m) * rstd * gam1 + bet1;
    if (q == 2) { act0[q] = tanhx(n0); act1[q] = tanhx(n1); }
    else        { act0[q] = sigm(n0);  act1[q] = sigm(n1); }
  }
  // c = f*c + i*g  (i=0, f=1, g=2, o=3)
  float c0 = act0[1] * sh_c[tid]       + act0[0] * act0[2];
  float c1 = act1[1] * sh_c[tid + 256] + act1[0] * act1[2];
  sh_c[tid] = c0; sh_c[tid + 256] = c1;
  float cs = c0 + c1, cq = c0 * c0 + c1 * c1;
#pragma unroll
  for (int o = 32; o; o >>= 1) { cs += __shfl_xor(cs, o); cq += __shfl_xor(cq, o); }
  if (lane == 0) { sh_redB[wave][0] = cs; sh_redB[wave][1] = cq; }
  __syncthreads();
  float ts = sh_redB[0][0] + sh_redB[1][0] + sh_redB[2][0] + sh_redB[3][0];
  float tq = sh_redB[0][1] + sh_redB[1][1] + sh_redB[2][1] + sh_redB[3][1];
  float m = ts * inv;
  float rstd = rsqrtf(fmaxf(tq * inv - m * m, 0.f) + 1e-5f);
  float h0 = act0[3] * tanhx((c0 - m) * rstd * gam0 + bet0);
  float h1 = act1[3] * tanhx((c1 - m) * rstd * gam1 + bet1);
  outv[tid] = h0; outv[tid + 256] = h1;
  if (ywr) { ywr[tid] = h0; ywr[tid + 256] = h1; }
  __syncthreads();
}

// ---------- main persistent recurrent kernel ----------
// R2 post-mortem: the allocator caps at 128 VGPRs regardless of waves_per_eu,
// so holding BOTH weight matrices in registers forced a per-step scratch
// reload (5.9 GB HBM/dispatch). New split that fits the 128-VGPR budget:
//   Wh0 rows -> registers (64 VGPRs, proven stable in R1/R2)
//   W1 rows  -> LDS (64 KB/block, loaded ONCE before the t-loop)
// Total LDS ~71.8 KB <= 80 KB/block at 2 blocks/CU (gfx950 has 160 KB/CU;
// >64KB static LDS is proven on gfx950 by learn_hip m201's 128 KiB kernel).

__global__ __launch_bounds__(BLOCK, 2)
void lstm_main(
    const unsigned short* __restrict__ Wh0,   // fp16 [B][2048][512]
    const unsigned short* __restrict__ W1,    // fp16 [B][2048][512]
    const float* __restrict__ g0x,            // fp32 [B][256][2048], bias0 folded in
    const float* __restrict__ bias1,
    const float* __restrict__ lnw,
    const float* __restrict__ lnb,
    float* __restrict__ gates0,
    float* __restrict__ gates1,
    unsigned* __restrict__ bar,
    float* __restrict__ y) {
  const int tid = threadIdx.x;
  const int wg = blockIdx.x;
  const int b = wg & 15;     // XCD-local: batch b's 32 WGs all on XCD b%8
  const int wgb = wg >> 4;
  const int wave = tid >> 6;
  const int lane = tid & 63;
  const int row0 = wgb * ROWS_PER_WG + wave * ROWS_PER_WAVE;

  __shared__ __align__(16) unsigned short sh_w1[ROWS_PER_WG][HH]; // 64 KB, persistent
  __shared__ __align__(16) float sh_h[HH];
  __shared__ __align__(16) float sh_c[HH];
  __shared__ __align__(16) float sh_in[HH];
  __shared__ float sh_redA[4][8];
  __shared__ float sh_redB[4][2];

  for (int i = tid; i < HH; i += BLOCK) { sh_h[i] = 0.f; sh_c[i] = 0.f; }

  // gamma/beta in registers
  const float gam0_l0 = lnw[tid],      gam1_l0 = lnw[tid + 256];
  const float gam0_l1 = lnw[HH + tid], gam1_l1 = lnw[HH + tid + 256];
  const float bet0_l0 = lnb[tid],      bet1_l0 = lnb[tid + 256];
  const float bet0_l1 = lnb[HH + tid], bet1_l1 = lnb[HH + tid + 256];

  unsigned* cnt = bar + b * 64;
  unsigned* gen = bar + b * 64 + 32;
  const size_t wbase = (size_t)b * G4 * HH;
  const unsigned short* __restrict__ Wh0b = Wh0 + wbase;
  const unsigned short* __restrict__ W1bp = W1 + wbase;
  float* g0b = gates0 + b * G4;
  float* g1b = gates1 + b * G4;

  // ---- Wh0 rows into registers (16 rows x 16B/lane = 64 VGPRs) ----
  uint4 wv0[ROWS_PER_WAVE];
#pragma unroll
  for (int r = 0; r < ROWS_PER_WAVE; ++r)
    wv0[r] = *(const uint4*)(Wh0b + (size_t)(row0 + r) * HH + lane * 8);
  // forbid rematerialization
#pragma unroll
  for (int r = 0; r < ROWS_PER_WAVE; ++r) {
    asm volatile("" : "+v"(wv0[r].x), "+v"(wv0[r].y), "+v"(wv0[r].z), "+v"(wv0[r].w));
  }

  // ---- W1 rows into LDS (64 rows x 512 fp16 = 64 KB, contiguous copy) ----
  {
    const uint4* w1src = (const uint4*)(W1bp + (size_t)wgb * ROWS_PER_WG * HH);
    uint4* w1dst = (uint4*)&sh_w1[0][0];
    for (int i = tid; i < ROWS_PER_WG * HH / 8; i += BLOCK)
      w1dst[i] = w1src[i];
  }

  // loop-invariant bias for phase B: lane l < 16 owns row row0+l (coalesced)
  const float bx = (lane < ROWS_PER_WAVE) ? bias1[b * G4 + row0 + lane] : 0.f;

  __syncthreads();

  for (int t = 0; t < SS; ++t) {
    const float* g0xt = g0x + ((size_t)b * SS + t) * G4;

    float4 ha = *(const float4*)&sh_h[lane * 8];
    float4 hb = *(const float4*)&sh_h[lane * 8 + 4];

    // phase A: gates0 = g0x[t] + Wh0 @ h   (weights in registers)
    {
      float accv[ROWS_PER_WAVE];
#pragma unroll
      for (int r = 0; r < ROWS_PER_WAVE; ++r)
        accv[r] = wave_sum(hdot8(wv0[r], ha, hb));
      float out = 0.f;
#pragma unroll
      for (int r = 0; r < ROWS_PER_WAVE; ++r) if (lane == r) out = accv[r];
      if (lane < ROWS_PER_WAVE)
        g0b[row0 + lane] = out + g0xt[row0 + lane];   // coalesced 16-lane store
    }
    batch_barrier(cnt, gen);

    // layer-0 pointwise -> h0 into sh_in (redundant per WG, deterministic)
    pointwise(g0b, sh_in, sh_c, gam0_l0, gam1_l0, bet0_l0, bet1_l0,
              sh_redA, sh_redB, nullptr);

    float4 va = *(const float4*)&sh_in[lane * 8];
    float4 vb = *(const float4*)&sh_in[lane * 8 + 4];

    // phase B: gates1 = (wih1+whh1) @ h0 + bias1  (weights from LDS)
    {
      float accv[ROWS_PER_WAVE];
#pragma unroll
      for (int r = 0; r < ROWS_PER_WAVE; ++r) {
        uint4 w = *(const uint4*)&sh_w1[wave * ROWS_PER_WAVE + r][lane * 8];
        accv[r] = wave_sum(hdot8(w, va, vb));
      }
      float out = 0.f;
#pragma unroll
      for (int r = 0; r < ROWS_PER_WAVE; ++r) if (lane == r) out = accv[r];
      if (lane < ROWS_PER_WAVE)
        g1b[row0 + lane] = out + bx;                  // coalesced 16-lane store
    }
    batch_barrier(cnt, gen);

    // layer-1 pointwise -> h into sh_h; leader WG writes y[b][t][:]
    float* ywr = (wgb == 0) ? (y + ((size_t)b * SS + t) * HH) : nullptr;
    pointwise(g1b, sh_h, sh_c, gam0_l1, gam1_l1, bet0_l1, bet1_l1,
              sh_redA, sh_redB, ywr);
  }
}

// ---------- launch ----------

extern "C" void kernel_launch(void* const* d_in, const int* in_sizes, int n_in,
                              void* d_out, int out_size, void* d_ws, size_t ws_size,
                              hipStream_t stream) {
  const float* x    = (const float*)d_in[0];
  const float* wih0 = (const float*)d_in[1];
  const float* whh0 = (const float*)d_in[2];
  const float* bih0 = (const float*)d_in[3];
  const float* bhh0 = (const float*)d_in[4];
  const float* wih1 = (const float*)d_in[5];
  const float* whh1 = (const float*)d_in[6];
  const float* bih1 = (const float*)d_in[7];
  const float* bhh1 = (const float*)d_in[8];
  const float* lnw  = (const float*)d_in[9];
  const float* lnb  = (const float*)d_in[10];
  float* y = (float*)d_out;

  char* ws = (char*)d_ws;
  const size_t WH = (size_t)BB * G4 * HH * 2;   // 33,554,432 B per fp16 matrix
  const size_t GX = (size_t)BB * SS * G4 * 4;   // 33,554,432 B g0x
  unsigned short* Wh0h = (unsigned short*)(ws);
  unsigned short* W1h  = (unsigned short*)(ws + WH);
  float* g0x   = (float*)(ws + 2 * WH);
  float* bias0 = (float*)(ws + 2 * WH + GX);
  float* bias1 = (float*)(ws + 2 * WH + GX + 131072);
  float* g0    = (float*)(ws + 2 * WH + GX + 2 * 131072);
  float* g1    = (float*)(ws + 2 * WH + GX + 3 * 131072);
  unsigned* bar = (unsigned*)(ws + 2 * WH + GX + 4 * 131072);

  hipLaunchKernelGGL(prep_kernel, dim3(4096), dim3(BLOCK), 0, stream,
                     whh0, wih1, whh1, bih0, bhh0, bih1, bhh1,
                     Wh0h, W1h, bias0, bias1, bar);

  hipLaunchKernelGGL(prep2_gemm, dim3(BB * 32), dim3(256), 0, stream,
                     wih0, x, bias0, g0x);

  void* args[] = { (void*)&Wh0h, (void*)&W1h, (void*)&g0x,
                   (void*)&bias1, (void*)&lnw, (void*)&lnb,
                   (void*)&g0, (void*)&g1, (void*)&bar, (void*)&y };
  hipError_t err = hipLaunchCooperativeKernel(reinterpret_cast<const void*>(&lstm_main),
                                              dim3(GRID), dim3(BLOCK), args, 0, stream);
  if (err != hipSuccess) {
    // fallback: plain launch — grid sized to guaranteed co-residency (2 blocks/CU)
    hipLaunchKernelGGL(lstm_main, dim3(GRID), dim3(BLOCK), 0, stream,
                       Wh0h, W1h, g0x, bias1, lnw, lnb, g0, g1, bar, y);
  }
}

// Round 4
// 9251.768 us; speedup vs baseline: 4.3556x; 1.5016x over previous
//
#include <hip/hip_runtime.h>
#include <hip/hip_fp16.h>

#define BB 16
#define SS 256
#define DD 512
#define HH 512
#define G4 2048                     // 4*H
#define BLOCK 256
#define WG_PER_B 32
#define GRID (BB * WG_PER_B)        // 512 blocks = 2 per CU (exact co-residency fit)
#define ROWS_PER_WG (G4 / WG_PER_B) // 64
#define ROWS_PER_WAVE (ROWS_PER_WG / 4) // 8? no: 64/4 = 16
#define FLAG_STRIDE 32              // 32 uints = 128 B between flag slots
#define FLAGS_PER_B (WG_PER_B * FLAG_STRIDE) // 1024 uints = 4 KB per batch

// ---------- helpers ----------

__device__ __forceinline__ float hdot8(uint4 w, float4 ha, float4 hb) {
  union { uint4 u; __half2 h[4]; } cv; cv.u = w;
  float2 f0 = __half22float2(cv.h[0]);
  float2 f1 = __half22float2(cv.h[1]);
  float2 f2 = __half22float2(cv.h[2]);
  float2 f3 = __half22float2(cv.h[3]);
  float acc;
  acc = f0.x * ha.x;
  acc = fmaf(f0.y, ha.y, acc);
  acc = fmaf(f1.x, ha.z, acc);
  acc = fmaf(f1.y, ha.w, acc);
  acc = fmaf(f2.x, hb.x, acc);
  acc = fmaf(f2.y, hb.y, acc);
  acc = fmaf(f3.x, hb.z, acc);
  acc = fmaf(f3.y, hb.w, acc);
  return acc;
}

__device__ __forceinline__ float wave_sum(float x) {
#pragma unroll
  for (int o = 32; o; o >>= 1) x += __shfl_xor(x, o);
  return x;
}

__device__ __forceinline__ float sigm(float x) { return 1.f / (1.f + __expf(-x)); }

__device__ __forceinline__ float tanhx(float x) {
  x = fminf(12.f, fmaxf(-12.f, x));
  float e = __expf(2.f * x);
  return (e - 1.f) / (e + 1.f);
}

// RMW-free per-batch barrier: each WG releases a monotonically increasing
// target into its OWN 128B-spaced flag slot; wave 0's lanes 0..31 poll all
// 32 slots (one vector load / iteration). No atomics RMW, no reset, no
// generation ping-pong -> no far-atomic serialization (R3: the ACQ_REL
// fetch_add + acquire-poll on shared lines cost ~25 us per barrier).
__device__ __forceinline__ void batch_barrier(unsigned* flags, int slot, unsigned target) {
  __syncthreads();   // all waves' stores issued & vmcnt-drained (L1 is write-through)
  if (threadIdx.x == 0) {
    __hip_atomic_store(&flags[slot * FLAG_STRIDE], target,
                       __ATOMIC_RELEASE, __HIP_MEMORY_SCOPE_AGENT);
  }
  if (threadIdx.x < WG_PER_B) {
    while (__hip_atomic_load(&flags[threadIdx.x * FLAG_STRIDE],
                             __ATOMIC_ACQUIRE, __HIP_MEMORY_SCOPE_AGENT) < target) {
      __builtin_amdgcn_s_sleep(1);
    }
  }
  __syncthreads();
}

// ---------- prep1: fp16 conversions, W1 = wih1+whh1, bias sums, flag init ----------

__global__ void prep_kernel(const float* __restrict__ whh0,
                            const float* __restrict__ wih1, const float* __restrict__ whh1,
                            const float* __restrict__ bih0, const float* __restrict__ bhh0,
                            const float* __restrict__ bih1, const float* __restrict__ bhh1,
                            unsigned short* __restrict__ Wh0h, unsigned short* __restrict__ W1h,
                            float* __restrict__ bias0, float* __restrict__ bias1,
                            unsigned* __restrict__ bar) {
  const int gid = blockIdx.x * BLOCK + threadIdx.x;
  const int stride = gridDim.x * BLOCK;
  const int N4 = BB * G4 * HH / 4;   // 4,194,304 float4s
  for (int i = gid; i < N4; i += stride) {
    float4 b = ((const float4*)whh0)[i];
    float4 c = ((const float4*)wih1)[i];
    float4 d = ((const float4*)whh1)[i];
    ushort4 rb, rc;
    rb.x = __half_as_ushort(__float2half_rn(b.x));
    rb.y = __half_as_ushort(__float2half_rn(b.y));
    rb.z = __half_as_ushort(__float2half_rn(b.z));
    rb.w = __half_as_ushort(__float2half_rn(b.w));
    rc.x = __half_as_ushort(__float2half_rn(c.x + d.x));
    rc.y = __half_as_ushort(__float2half_rn(c.y + d.y));
    rc.z = __half_as_ushort(__float2half_rn(c.z + d.z));
    rc.w = __half_as_ushort(__float2half_rn(c.w + d.w));
    ((ushort4*)Wh0h)[i] = rb;
    ((ushort4*)W1h)[i]  = rc;
  }
  if (gid < BB * G4 / 4) {
    float4 p = ((const float4*)bih0)[gid];
    float4 q = ((const float4*)bhh0)[gid];
    ((float4*)bias0)[gid] = make_float4(p.x + q.x, p.y + q.y, p.z + q.z, p.w + q.w);
    p = ((const float4*)bih1)[gid];
    q = ((const float4*)bhh1)[gid];
    ((float4*)bias1)[gid] = make_float4(p.x + q.x, p.y + q.y, p.z + q.z, p.w + q.w);
  }
  if (gid < BB * FLAGS_PER_B) bar[gid] = 0u;   // 16 KB of flags, zeroed
}

// ---------- prep2: g0x[b][t][row] = sum_k Wih0[b][row][k]*x[b][t][k] + bias0[b][row] ----------

__global__ __launch_bounds__(256) void prep2_gemm(const float* __restrict__ wih0,
                                                  const float* __restrict__ x,
                                                  const float* __restrict__ bias0,
                                                  float* __restrict__ g0x) {
  __shared__ float As[32][132];  // [k][row], +4 pad keeps 16B align & spreads banks
  __shared__ float Xs[32][132];  // [k][t]
  const int bid = blockIdx.x;
  const int b  = bid >> 5;
  const int rt = (bid >> 1) & 15;
  const int tt = bid & 1;
  const int tid = threadIdx.x;
  const int tr = tid & 15;    // row-group
  const int tg = tid >> 4;    // t-group

  float acc[8][8];
#pragma unroll
  for (int i = 0; i < 8; ++i)
#pragma unroll
    for (int j = 0; j < 8; ++j) acc[i][j] = 0.f;

  const float* Wb = wih0 + ((size_t)b * G4 + rt * 128) * DD;
  const float* Xb = x + ((size_t)b * SS + tt * 128) * DD;
  const int lr = tid >> 3;   // 0..31
  const int lc = tid & 7;    // 0..7

  for (int kc = 0; kc < DD; kc += 32) {
#pragma unroll
    for (int p = 0; p < 4; ++p) {
      const int row = lr + p * 32;   // 0..127
      float4 w = *(const float4*)(Wb + (size_t)row * DD + kc + lc * 4);
      As[lc * 4 + 0][row] = w.x; As[lc * 4 + 1][row] = w.y;
      As[lc * 4 + 2][row] = w.z; As[lc * 4 + 3][row] = w.w;
      float4 xv = *(const float4*)(Xb + (size_t)row * DD + kc + lc * 4);
      Xs[lc * 4 + 0][row] = xv.x; Xs[lc * 4 + 1][row] = xv.y;
      Xs[lc * 4 + 2][row] = xv.z; Xs[lc * 4 + 3][row] = xv.w;
    }
    __syncthreads();
#pragma unroll
    for (int k = 0; k < 32; ++k) {
      float4 a0 = *(const float4*)&As[k][tr * 8];
      float4 a1 = *(const float4*)&As[k][tr * 8 + 4];
      float4 b0 = *(const float4*)&Xs[k][tg * 8];
      float4 b1 = *(const float4*)&Xs[k][tg * 8 + 4];
      float av[8] = {a0.x, a0.y, a0.z, a0.w, a1.x, a1.y, a1.z, a1.w};
      float bv[8] = {b0.x, b0.y, b0.z, b0.w, b1.x, b1.y, b1.z, b1.w};
#pragma unroll
      for (int i = 0; i < 8; ++i)
#pragma unroll
        for (int j = 0; j < 8; ++j) acc[i][j] = fmaf(av[i], bv[j], acc[i][j]);
    }
    __syncthreads();
  }

  const int r0g = rt * 128 + tr * 8;
  const int t0g = tt * 128 + tg * 8;
  float bv[8];
#pragma unroll
  for (int i = 0; i < 8; ++i) bv[i] = bias0[b * G4 + r0g + i];
#pragma unroll
  for (int j = 0; j < 8; ++j) {
    float* op = g0x + ((size_t)(b * SS + t0g + j)) * G4 + r0g;
    float4 o0 = make_float4(acc[0][j] + bv[0], acc[1][j] + bv[1], acc[2][j] + bv[2], acc[3][j] + bv[3]);
    float4 o1 = make_float4(acc[4][j] + bv[4], acc[5][j] + bv[5], acc[6][j] + bv[6], acc[7][j] + bv[7]);
    ((float4*)op)[0] = o0;
    ((float4*)op)[1] = o1;
  }
}

// ---------- pointwise: LN x4 gates + activations + c update + LN(c) -> out vec ----------
// Gates read directly from global (coalesced, L2-hit, each value read once).

__device__ __forceinline__ void pointwise(
    const float* __restrict__ gsrc, float* __restrict__ outv,
    float* sh_c,
    float gam0, float gam1, float bet0, float bet1,
    float (*sh_redA)[8], float (*sh_redB)[2], float* ywr) {
  const int tid = threadIdx.x;
  const int wave = tid >> 6, lane = tid & 63;

  float a0[4], a1[4], sv[4], qv[4];
#pragma unroll
  for (int q = 0; q < 4; ++q) {
    a0[q] = gsrc[q * HH + tid];
    a1[q] = gsrc[q * HH + 256 + tid];
    sv[q] = a0[q] + a1[q];
    qv[q] = a0[q] * a0[q] + a1[q] * a1[q];
  }
#pragma unroll
  for (int o = 32; o; o >>= 1) {
#pragma unroll
    for (int q = 0; q < 4; ++q) {
      sv[q] += __shfl_xor(sv[q], o);
      qv[q] += __shfl_xor(qv[q], o);
    }
  }
  if (lane == 0) {
#pragma unroll
    for (int q = 0; q < 4; ++q) { sh_redA[wave][q] = sv[q]; sh_redA[wave][q + 4] = qv[q]; }
  }
  __syncthreads();

  const float inv = 1.f / (float)HH;
  float act0[4], act1[4];
#pragma unroll
  for (int q = 0; q < 4; ++q) {
    float ts = sh_redA[0][q] + sh_redA[1][q] + sh_redA[2][q] + sh_redA[3][q];
    float tq = sh_redA[0][q + 4] + sh_redA[1][q + 4] + sh_redA[2][q + 4] + sh_redA[3][q + 4];
    float m = ts * inv;
    float var = fmaxf(tq * inv - m * m, 0.f);
    float rstd = rsqrtf(var + 1e-5f);
    float n0 = (a0[q] - m) * rstd * gam0 + bet0;
    float n1 = (a1[q] - m) * rstd * gam1 + bet1;
    if (q == 2) { act0[q] = tanhx(n0); act1[q] = tanhx(n1); }
    else        { act0[q] = sigm(n0);  act1[q] = sigm(n1); }
  }
  // c = f*c + i*g  (i=0, f=1, g=2, o=3)
  float c0 = act0[1] * sh_c[tid]       + act0[0] * act0[2];
  float c1 = act1[1] * sh_c[tid + 256] + act1[0] * act1[2];
  sh_c[tid] = c0; sh_c[tid + 256] = c1;
  float cs = c0 + c1, cq = c0 * c0 + c1 * c1;
#pragma unroll
  for (int o = 32; o; o >>= 1) { cs += __shfl_xor(cs, o); cq += __shfl_xor(cq, o); }
  if (lane == 0) { sh_redB[wave][0] = cs; sh_redB[wave][1] = cq; }
  __syncthreads();
  float ts = sh_redB[0][0] + sh_redB[1][0] + sh_redB[2][0] + sh_redB[3][0];
  float tq = sh_redB[0][1] + sh_redB[1][1] + sh_redB[2][1] + sh_redB[3][1];
  float m = ts * inv;
  float rstd = rsqrtf(fmaxf(tq * inv - m * m, 0.f) + 1e-5f);
  float h0 = act0[3] * tanhx((c0 - m) * rstd * gam0 + bet0);
  float h1 = act1[3] * tanhx((c1 - m) * rstd * gam1 + bet1);
  outv[tid] = h0; outv[tid + 256] = h1;
  if (ywr) { ywr[tid] = h0; ywr[tid + 256] = h1; }
  __syncthreads();
}

// ---------- main persistent recurrent kernel ----------
// Wh0 rows in registers (64 VGPRs), W1 rows in LDS (64 KB, loaded once).
// Inter-WG sync: RMW-free flag barrier (see batch_barrier).

__global__ __launch_bounds__(BLOCK, 2)
void lstm_main(
    const unsigned short* __restrict__ Wh0,   // fp16 [B][2048][512]
    const unsigned short* __restrict__ W1,    // fp16 [B][2048][512]
    const float* __restrict__ g0x,            // fp32 [B][256][2048], bias0 folded in
    const float* __restrict__ bias1,
    const float* __restrict__ lnw,
    const float* __restrict__ lnb,
    float* __restrict__ gates0,
    float* __restrict__ gates1,
    unsigned* __restrict__ bar,
    float* __restrict__ y) {
  const int tid = threadIdx.x;
  const int wg = blockIdx.x;
  const int b = wg & 15;     // XCD-local heuristic: batch b's 32 WGs on XCD b%8
  const int wgb = wg >> 4;
  const int wave = tid >> 6;
  const int lane = tid & 63;
  const int row0 = wgb * ROWS_PER_WG + wave * (ROWS_PER_WG / 4);
  const int RPW = ROWS_PER_WG / 4;   // 16 rows per wave

  __shared__ __align__(16) unsigned short sh_w1[ROWS_PER_WG][HH]; // 64 KB, persistent
  __shared__ __align__(16) float sh_h[HH];
  __shared__ __align__(16) float sh_c[HH];
  __shared__ __align__(16) float sh_in[HH];
  __shared__ float sh_redA[4][8];
  __shared__ float sh_redB[4][2];

  for (int i = tid; i < HH; i += BLOCK) { sh_h[i] = 0.f; sh_c[i] = 0.f; }

  // gamma/beta in registers
  const float gam0_l0 = lnw[tid],      gam1_l0 = lnw[tid + 256];
  const float gam0_l1 = lnw[HH + tid], gam1_l1 = lnw[HH + tid + 256];
  const float bet0_l0 = lnb[tid],      bet1_l0 = lnb[tid + 256];
  const float bet0_l1 = lnb[HH + tid], bet1_l1 = lnb[HH + tid + 256];

  unsigned* flags = bar + b * FLAGS_PER_B;
  const size_t wbase = (size_t)b * G4 * HH;
  const unsigned short* __restrict__ Wh0b = Wh0 + wbase;
  const unsigned short* __restrict__ W1bp = W1 + wbase;
  float* g0b = gates0 + b * G4;
  float* g1b = gates1 + b * G4;

  // ---- Wh0 rows into registers (16 rows x 16B/lane = 64 VGPRs) ----
  uint4 wv0[16];
#pragma unroll
  for (int r = 0; r < 16; ++r)
    wv0[r] = *(const uint4*)(Wh0b + (size_t)(row0 + r) * HH + lane * 8);
  // forbid rematerialization
#pragma unroll
  for (int r = 0; r < 16; ++r) {
    asm volatile("" : "+v"(wv0[r].x), "+v"(wv0[r].y), "+v"(wv0[r].z), "+v"(wv0[r].w));
  }

  // ---- W1 rows into LDS (64 rows x 512 fp16 = 64 KB, contiguous copy) ----
  {
    const uint4* w1src = (const uint4*)(W1bp + (size_t)wgb * ROWS_PER_WG * HH);
    uint4* w1dst = (uint4*)&sh_w1[0][0];
    for (int i = tid; i < ROWS_PER_WG * HH / 8; i += BLOCK)
      w1dst[i] = w1src[i];
  }

  // loop-invariant bias for phase B: lane l < 16 owns row row0+l (coalesced)
  const float bx = (lane < RPW) ? bias1[b * G4 + row0 + lane] : 0.f;

  __syncthreads();

  for (int t = 0; t < SS; ++t) {
    const float* g0xt = g0x + ((size_t)b * SS + t) * G4;

    // prefetch this step's g0x slice early (independent of h)
    float gx = 0.f;
    if (lane < RPW) gx = g0xt[row0 + lane];

    float4 ha = *(const float4*)&sh_h[lane * 8];
    float4 hb = *(const float4*)&sh_h[lane * 8 + 4];

    // phase A: gates0 = g0x[t] + Wh0 @ h   (weights in registers)
    {
      float accv[16];
#pragma unroll
      for (int r = 0; r < 16; ++r)
        accv[r] = wave_sum(hdot8(wv0[r], ha, hb));
      float out = 0.f;
#pragma unroll
      for (int r = 0; r < 16; ++r) if (lane == r) out = accv[r];
      if (lane < RPW)
        g0b[row0 + lane] = out + gx;                  // coalesced 16-lane store
    }
    batch_barrier(flags, wgb, 2u * t + 1u);

    // layer-0 pointwise -> h0 into sh_in (redundant per WG, deterministic)
    pointwise(g0b, sh_in, sh_c, gam0_l0, gam1_l0, bet0_l0, bet1_l0,
              sh_redA, sh_redB, nullptr);

    float4 va = *(const float4*)&sh_in[lane * 8];
    float4 vb = *(const float4*)&sh_in[lane * 8 + 4];

    // phase B: gates1 = (wih1+whh1) @ h0 + bias1  (weights from LDS)
    {
      float accv[16];
#pragma unroll
      for (int r = 0; r < 16; ++r) {
        uint4 w = *(const uint4*)&sh_w1[wave * RPW + r][lane * 8];
        accv[r] = wave_sum(hdot8(w, va, vb));
      }
      float out = 0.f;
#pragma unroll
      for (int r = 0; r < 16; ++r) if (lane == r) out = accv[r];
      if (lane < RPW)
        g1b[row0 + lane] = out + bx;                  // coalesced 16-lane store
    }
    batch_barrier(flags, wgb, 2u * t + 2u);

    // layer-1 pointwise -> h into sh_h; leader WG writes y[b][t][:]
    float* ywr = (wgb == 0) ? (y + ((size_t)b * SS + t) * HH) : nullptr;
    pointwise(g1b, sh_h, sh_c, gam0_l1, gam1_l1, bet0_l1, bet1_l1,
              sh_redA, sh_redB, ywr);
  }
}

// ---------- launch ----------

extern "C" void kernel_launch(void* const* d_in, const int* in_sizes, int n_in,
                              void* d_out, int out_size, void* d_ws, size_t ws_size,
                              hipStream_t stream) {
  const float* x    = (const float*)d_in[0];
  const float* wih0 = (const float*)d_in[1];
  const float* whh0 = (const float*)d_in[2];
  const float* bih0 = (const float*)d_in[3];
  const float* bhh0 = (const float*)d_in[4];
  const float* wih1 = (const float*)d_in[5];
  const float* whh1 = (const float*)d_in[6];
  const float* bih1 = (const float*)d_in[7];
  const float* bhh1 = (const float*)d_in[8];
  const float* lnw  = (const float*)d_in[9];
  const float* lnb  = (const float*)d_in[10];
  float* y = (float*)d_out;

  char* ws = (char*)d_ws;
  const size_t WH = (size_t)BB * G4 * HH * 2;   // 33,554,432 B per fp16 matrix
  const size_t GX = (size_t)BB * SS * G4 * 4;   // 33,554,432 B g0x
  unsigned short* Wh0h = (unsigned short*)(ws);
  unsigned short* W1h  = (unsigned short*)(ws + WH);
  float* g0x   = (float*)(ws + 2 * WH);
  float* bias0 = (float*)(ws + 2 * WH + GX);
  float* bias1 = (float*)(ws + 2 * WH + GX + 131072);
  float* g0    = (float*)(ws + 2 * WH + GX + 2 * 131072);
  float* g1    = (float*)(ws + 2 * WH + GX + 3 * 131072);
  unsigned* bar = (unsigned*)(ws + 2 * WH + GX + 4 * 131072);  // 16*4KB = 64 KB flags

  hipLaunchKernelGGL(prep_kernel, dim3(4096), dim3(BLOCK), 0, stream,
                     whh0, wih1, whh1, bih0, bhh0, bih1, bhh1,
                     Wh0h, W1h, bias0, bias1, bar);

  hipLaunchKernelGGL(prep2_gemm, dim3(BB * 32), dim3(256), 0, stream,
                     wih0, x, bias0, g0x);

  void* args[] = { (void*)&Wh0h, (void*)&W1h, (void*)&g0x,
                   (void*)&bias1, (void*)&lnw, (void*)&lnb,
                   (void*)&g0, (void*)&g1, (void*)&bar, (void*)&y };
  hipError_t err = hipLaunchCooperativeKernel(reinterpret_cast<const void*>(&lstm_main),
                                              dim3(GRID), dim3(BLOCK), args, 0, stream);
  if (err != hipSuccess) {
    // fallback: plain launch — grid sized to guaranteed co-residency (2 blocks/CU)
    hipLaunchKernelGGL(lstm_main, dim3(GRID), dim3(BLOCK), 0, stream,
                       Wh0h, W1h, g0x, bias1, lnw, lnb, g0, g1, bar, y);
  }
}

// Round 5
// 3624.700 us; speedup vs baseline: 11.1174x; 2.5524x over previous
//
#include <hip/hip_runtime.h>
#include <hip/hip_fp16.h>

#define BB 16
#define SS 256
#define DD 512
#define HH 512
#define G4 2048                     // 4*H
#define BLOCK 256
#define WG_PER_B 32
#define GRID (BB * WG_PER_B)        // 512 blocks = 2 per CU (exact co-residency fit)
#define ROWS_PER_WG (G4 / WG_PER_B) // 64
#define FLAG_STRIDE 32              // 32 uints = 128 B between flag slots
#define FLAGS_PER_B (WG_PER_B * FLAG_STRIDE) // 1024 uints = 4 KB per batch

// ---------- helpers ----------

__device__ __forceinline__ float hdot8(uint4 w, float4 ha, float4 hb) {
  union { uint4 u; __half2 h[4]; } cv; cv.u = w;
  float2 f0 = __half22float2(cv.h[0]);
  float2 f1 = __half22float2(cv.h[1]);
  float2 f2 = __half22float2(cv.h[2]);
  float2 f3 = __half22float2(cv.h[3]);
  float acc;
  acc = f0.x * ha.x;
  acc = fmaf(f0.y, ha.y, acc);
  acc = fmaf(f1.x, ha.z, acc);
  acc = fmaf(f1.y, ha.w, acc);
  acc = fmaf(f2.x, hb.x, acc);
  acc = fmaf(f2.y, hb.y, acc);
  acc = fmaf(f3.x, hb.z, acc);
  acc = fmaf(f3.y, hb.w, acc);
  return acc;
}

__device__ __forceinline__ float wave_sum(float x) {
#pragma unroll
  for (int o = 32; o; o >>= 1) x += __shfl_xor(x, o);
  return x;
}

__device__ __forceinline__ float sigm(float x) { return 1.f / (1.f + __expf(-x)); }

__device__ __forceinline__ float tanhx(float x) {
  x = fminf(12.f, fmaxf(-12.f, x));
  float e = __expf(2.f * x);
  return (e - 1.f) / (e + 1.f);
}

// Fence-free per-batch barrier. R4 post-mortem: agent-scope REL/ACQ emit
// buffer_wbl2 / L2-invalidate on gfx950 (per-XCD L2s, coherence point is
// memory-side) -> every barrier flushed+invalidated L2 (~30 us/step, and
// WRITE_SIZE showed the per-step gates hitting HBM). All cross-WG payloads
// are relaxed AGENT atomics (sc1: operate at the coherence point directly),
// so no fences are needed:
//  - __syncthreads() drains vmcnt => this WG's gate stores are at the
//    coherence point before thread 0 publishes the flag (relaxed store).
//  - pollers use relaxed loads; loop-exit control dependence + the
//    workgroup-scope acquire fence (cheap: no cache invalidate) order the
//    subsequent data loads.
__device__ __forceinline__ void batch_barrier(unsigned* flags, int slot, unsigned target) {
  __syncthreads();   // compiler emits s_waitcnt vmcnt(0) before s_barrier
  if (threadIdx.x == 0) {
    __hip_atomic_store(&flags[slot * FLAG_STRIDE], target,
                       __ATOMIC_RELAXED, __HIP_MEMORY_SCOPE_AGENT);
  }
  if (threadIdx.x < WG_PER_B) {
    while (__hip_atomic_load(&flags[threadIdx.x * FLAG_STRIDE],
                             __ATOMIC_RELAXED, __HIP_MEMORY_SCOPE_AGENT) < target) {
      __builtin_amdgcn_s_sleep(1);
    }
  }
  __builtin_amdgcn_fence(__ATOMIC_ACQUIRE, "workgroup");  // compiler/issue ordering only
  __syncthreads();
}

// ---------- prep1: fp16 conversions, W1 = wih1+whh1, bias sums, flag init ----------

__global__ void prep_kernel(const float* __restrict__ whh0,
                            const float* __restrict__ wih1, const float* __restrict__ whh1,
                            const float* __restrict__ bih0, const float* __restrict__ bhh0,
                            const float* __restrict__ bih1, const float* __restrict__ bhh1,
                            unsigned short* __restrict__ Wh0h, unsigned short* __restrict__ W1h,
                            float* __restrict__ bias0, float* __restrict__ bias1,
                            unsigned* __restrict__ bar) {
  const int gid = blockIdx.x * BLOCK + threadIdx.x;
  const int stride = gridDim.x * BLOCK;
  const int N4 = BB * G4 * HH / 4;   // 4,194,304 float4s
  for (int i = gid; i < N4; i += stride) {
    float4 b = ((const float4*)whh0)[i];
    float4 c = ((const float4*)wih1)[i];
    float4 d = ((const float4*)whh1)[i];
    ushort4 rb, rc;
    rb.x = __half_as_ushort(__float2half_rn(b.x));
    rb.y = __half_as_ushort(__float2half_rn(b.y));
    rb.z = __half_as_ushort(__float2half_rn(b.z));
    rb.w = __half_as_ushort(__float2half_rn(b.w));
    rc.x = __half_as_ushort(__float2half_rn(c.x + d.x));
    rc.y = __half_as_ushort(__float2half_rn(c.y + d.y));
    rc.z = __half_as_ushort(__float2half_rn(c.z + d.z));
    rc.w = __half_as_ushort(__float2half_rn(c.w + d.w));
    ((ushort4*)Wh0h)[i] = rb;
    ((ushort4*)W1h)[i]  = rc;
  }
  if (gid < BB * G4 / 4) {
    float4 p = ((const float4*)bih0)[gid];
    float4 q = ((const float4*)bhh0)[gid];
    ((float4*)bias0)[gid] = make_float4(p.x + q.x, p.y + q.y, p.z + q.z, p.w + q.w);
    p = ((const float4*)bih1)[gid];
    q = ((const float4*)bhh1)[gid];
    ((float4*)bias1)[gid] = make_float4(p.x + q.x, p.y + q.y, p.z + q.z, p.w + q.w);
  }
  if (gid < BB * FLAGS_PER_B) bar[gid] = 0u;   // 64 KB of flags, zeroed
}

// ---------- prep2: g0x[b][t][row] = sum_k Wih0[b][row][k]*x[b][t][k] + bias0[b][row] ----------

__global__ __launch_bounds__(256) void prep2_gemm(const float* __restrict__ wih0,
                                                  const float* __restrict__ x,
                                                  const float* __restrict__ bias0,
                                                  float* __restrict__ g0x) {
  __shared__ float As[32][132];  // [k][row], +4 pad keeps 16B align & spreads banks
  __shared__ float Xs[32][132];  // [k][t]
  const int bid = blockIdx.x;
  const int b  = bid >> 5;
  const int rt = (bid >> 1) & 15;
  const int tt = bid & 1;
  const int tid = threadIdx.x;
  const int tr = tid & 15;    // row-group
  const int tg = tid >> 4;    // t-group

  float acc[8][8];
#pragma unroll
  for (int i = 0; i < 8; ++i)
#pragma unroll
    for (int j = 0; j < 8; ++j) acc[i][j] = 0.f;

  const float* Wb = wih0 + ((size_t)b * G4 + rt * 128) * DD;
  const float* Xb = x + ((size_t)b * SS + tt * 128) * DD;
  const int lr = tid >> 3;   // 0..31
  const int lc = tid & 7;    // 0..7

  for (int kc = 0; kc < DD; kc += 32) {
#pragma unroll
    for (int p = 0; p < 4; ++p) {
      const int row = lr + p * 32;   // 0..127
      float4 w = *(const float4*)(Wb + (size_t)row * DD + kc + lc * 4);
      As[lc * 4 + 0][row] = w.x; As[lc * 4 + 1][row] = w.y;
      As[lc * 4 + 2][row] = w.z; As[lc * 4 + 3][row] = w.w;
      float4 xv = *(const float4*)(Xb + (size_t)row * DD + kc + lc * 4);
      Xs[lc * 4 + 0][row] = xv.x; Xs[lc * 4 + 1][row] = xv.y;
      Xs[lc * 4 + 2][row] = xv.z; Xs[lc * 4 + 3][row] = xv.w;
    }
    __syncthreads();
#pragma unroll
    for (int k = 0; k < 32; ++k) {
      float4 a0 = *(const float4*)&As[k][tr * 8];
      float4 a1 = *(const float4*)&As[k][tr * 8 + 4];
      float4 b0 = *(const float4*)&Xs[k][tg * 8];
      float4 b1 = *(const float4*)&Xs[k][tg * 8 + 4];
      float av[8] = {a0.x, a0.y, a0.z, a0.w, a1.x, a1.y, a1.z, a1.w};
      float bv[8] = {b0.x, b0.y, b0.z, b0.w, b1.x, b1.y, b1.z, b1.w};
#pragma unroll
      for (int i = 0; i < 8; ++i)
#pragma unroll
        for (int j = 0; j < 8; ++j) acc[i][j] = fmaf(av[i], bv[j], acc[i][j]);
    }
    __syncthreads();
  }

  const int r0g = rt * 128 + tr * 8;
  const int t0g = tt * 128 + tg * 8;
  float bv[8];
#pragma unroll
  for (int i = 0; i < 8; ++i) bv[i] = bias0[b * G4 + r0g + i];
#pragma unroll
  for (int j = 0; j < 8; ++j) {
    float* op = g0x + ((size_t)(b * SS + t0g + j)) * G4 + r0g;
    float4 o0 = make_float4(acc[0][j] + bv[0], acc[1][j] + bv[1], acc[2][j] + bv[2], acc[3][j] + bv[3]);
    float4 o1 = make_float4(acc[4][j] + bv[4], acc[5][j] + bv[5], acc[6][j] + bv[6], acc[7][j] + bv[7]);
    ((float4*)op)[0] = o0;
    ((float4*)op)[1] = o1;
  }
}

// ---------- pointwise: LN x4 gates + activations + c update + LN(c) -> out vec ----------
// Cross-WG gate reads are relaxed AGENT atomic loads (coherence-point reads,
// no cache invalidation). 8 independent loads issue back-to-back -> one
// latency exposure. gamma/beta in registers.

__device__ __forceinline__ void pointwise(
    const float* __restrict__ gsrc, float* __restrict__ outv,
    float* sh_c,
    float gam0, float gam1, float bet0, float bet1,
    float (*sh_redA)[8], float (*sh_redB)[2], float* ywr) {
  const int tid = threadIdx.x;
  const int wave = tid >> 6, lane = tid & 63;

  float a0[4], a1[4], sv[4], qv[4];
#pragma unroll
  for (int q = 0; q < 4; ++q) {
    a0[q] = __hip_atomic_load(&gsrc[q * HH + tid],
                              __ATOMIC_RELAXED, __HIP_MEMORY_SCOPE_AGENT);
    a1[q] = __hip_atomic_load(&gsrc[q * HH + 256 + tid],
                              __ATOMIC_RELAXED, __HIP_MEMORY_SCOPE_AGENT);
  }
#pragma unroll
  for (int q = 0; q < 4; ++q) {
    sv[q] = a0[q] + a1[q];
    qv[q] = a0[q] * a0[q] + a1[q] * a1[q];
  }
#pragma unroll
  for (int o = 32; o; o >>= 1) {
#pragma unroll
    for (int q = 0; q < 4; ++q) {
      sv[q] += __shfl_xor(sv[q], o);
      qv[q] += __shfl_xor(qv[q], o);
    }
  }
  if (lane == 0) {
#pragma unroll
    for (int q = 0; q < 4; ++q) { sh_redA[wave][q] = sv[q]; sh_redA[wave][q + 4] = qv[q]; }
  }
  __syncthreads();

  const float inv = 1.f / (float)HH;
  float act0[4], act1[4];
#pragma unroll
  for (int q = 0; q < 4; ++q) {
    float ts = sh_redA[0][q] + sh_redA[1][q] + sh_redA[2][q] + sh_redA[3][q];
    float tq = sh_redA[0][q + 4] + sh_redA[1][q + 4] + sh_redA[2][q + 4] + sh_redA[3][q + 4];
    float m = ts * inv;
    float var = fmaxf(tq * inv - m * m, 0.f);
    float rstd = rsqrtf(var + 1e-5f);
    float n0 = (a0[q] - m) * rstd * gam0 + bet0;
    float n1 = (a1[q] - m) * rstd * gam1 + bet1;
    if (q == 2) { act0[q] = tanhx(n0); act1[q] = tanhx(n1); }
    else        { act0[q] = sigm(n0);  act1[q] = sigm(n1); }
  }
  // c = f*c + i*g  (i=0, f=1, g=2, o=3)
  float c0 = act0[1] * sh_c[tid]       + act0[0] * act0[2];
  float c1 = act1[1] * sh_c[tid + 256] + act1[0] * act1[2];
  sh_c[tid] = c0; sh_c[tid + 256] = c1;
  float cs = c0 + c1, cq = c0 * c0 + c1 * c1;
#pragma unroll
  for (int o = 32; o; o >>= 1) { cs += __shfl_xor(cs, o); cq += __shfl_xor(cq, o); }
  if (lane == 0) { sh_redB[wave][0] = cs; sh_redB[wave][1] = cq; }
  __syncthreads();
  float ts = sh_redB[0][0] + sh_redB[1][0] + sh_redB[2][0] + sh_redB[3][0];
  float tq = sh_redB[0][1] + sh_redB[1][1] + sh_redB[2][1] + sh_redB[3][1];
  float m = ts * inv;
  float rstd = rsqrtf(fmaxf(tq * inv - m * m, 0.f) + 1e-5f);
  float h0 = act0[3] * tanhx((c0 - m) * rstd * gam0 + bet0);
  float h1 = act1[3] * tanhx((c1 - m) * rstd * gam1 + bet1);
  outv[tid] = h0; outv[tid + 256] = h1;
  if (ywr) { ywr[tid] = h0; ywr[tid + 256] = h1; }
  __syncthreads();
}

// ---------- main persistent recurrent kernel ----------
// Wh0 rows in registers (64 VGPRs), W1 rows in LDS (64 KB, loaded once).
// Inter-WG sync: fence-free relaxed-atomic flag barrier (see batch_barrier).

__global__ __launch_bounds__(BLOCK, 2)
void lstm_main(
    const unsigned short* __restrict__ Wh0,   // fp16 [B][2048][512]
    const unsigned short* __restrict__ W1,    // fp16 [B][2048][512]
    const float* __restrict__ g0x,            // fp32 [B][256][2048], bias0 folded in
    const float* __restrict__ bias1,
    const float* __restrict__ lnw,
    const float* __restrict__ lnb,
    float* __restrict__ gates0,
    float* __restrict__ gates1,
    unsigned* __restrict__ bar,
    float* __restrict__ y) {
  const int tid = threadIdx.x;
  const int wg = blockIdx.x;
  const int b = wg & 15;     // XCD-local heuristic (perf only, not correctness)
  const int wgb = wg >> 4;
  const int wave = tid >> 6;
  const int lane = tid & 63;
  const int row0 = wgb * ROWS_PER_WG + wave * (ROWS_PER_WG / 4);
  const int RPW = ROWS_PER_WG / 4;   // 16 rows per wave

  __shared__ __align__(16) unsigned short sh_w1[ROWS_PER_WG][HH]; // 64 KB, persistent
  __shared__ __align__(16) float sh_h[HH];
  __shared__ __align__(16) float sh_c[HH];
  __shared__ __align__(16) float sh_in[HH];
  __shared__ float sh_redA[4][8];
  __shared__ float sh_redB[4][2];

  for (int i = tid; i < HH; i += BLOCK) { sh_h[i] = 0.f; sh_c[i] = 0.f; }

  // gamma/beta in registers
  const float gam0_l0 = lnw[tid],      gam1_l0 = lnw[tid + 256];
  const float gam0_l1 = lnw[HH + tid], gam1_l1 = lnw[HH + tid + 256];
  const float bet0_l0 = lnb[tid],      bet1_l0 = lnb[tid + 256];
  const float bet0_l1 = lnb[HH + tid], bet1_l1 = lnb[HH + tid + 256];

  unsigned* flags = bar + b * FLAGS_PER_B;
  const size_t wbase = (size_t)b * G4 * HH;
  const unsigned short* __restrict__ Wh0b = Wh0 + wbase;
  const unsigned short* __restrict__ W1bp = W1 + wbase;
  float* g0b = gates0 + b * G4;
  float* g1b = gates1 + b * G4;

  // ---- Wh0 rows into registers (16 rows x 16B/lane = 64 VGPRs) ----
  uint4 wv0[16];
#pragma unroll
  for (int r = 0; r < 16; ++r)
    wv0[r] = *(const uint4*)(Wh0b + (size_t)(row0 + r) * HH + lane * 8);
  // forbid rematerialization
#pragma unroll
  for (int r = 0; r < 16; ++r) {
    asm volatile("" : "+v"(wv0[r].x), "+v"(wv0[r].y), "+v"(wv0[r].z), "+v"(wv0[r].w));
  }

  // ---- W1 rows into LDS (64 rows x 512 fp16 = 64 KB, contiguous copy) ----
  {
    const uint4* w1src = (const uint4*)(W1bp + (size_t)wgb * ROWS_PER_WG * HH);
    uint4* w1dst = (uint4*)&sh_w1[0][0];
    for (int i = tid; i < ROWS_PER_WG * HH / 8; i += BLOCK)
      w1dst[i] = w1src[i];
  }

  // loop-invariant bias for phase B: lane l < 16 owns row row0+l (coalesced)
  const float bx = (lane < RPW) ? bias1[b * G4 + row0 + lane] : 0.f;

  __syncthreads();

  for (int t = 0; t < SS; ++t) {
    const float* g0xt = g0x + ((size_t)b * SS + t) * G4;

    // prefetch this step's g0x slice early (independent of h)
    float gx = 0.f;
    if (lane < RPW) gx = g0xt[row0 + lane];

    float4 ha = *(const float4*)&sh_h[lane * 8];
    float4 hb = *(const float4*)&sh_h[lane * 8 + 4];

    // phase A: gates0 = g0x[t] + Wh0 @ h   (weights in registers)
    {
      float accv[16];
#pragma unroll
      for (int r = 0; r < 16; ++r)
        accv[r] = wave_sum(hdot8(wv0[r], ha, hb));
      float out = 0.f;
#pragma unroll
      for (int r = 0; r < 16; ++r) if (lane == r) out = accv[r];
      if (lane < RPW)
        __hip_atomic_store(&g0b[row0 + lane], out + gx,
                           __ATOMIC_RELAXED, __HIP_MEMORY_SCOPE_AGENT);
    }
    batch_barrier(flags, wgb, 2u * t + 1u);

    // layer-0 pointwise -> h0 into sh_in (redundant per WG, deterministic)
    pointwise(g0b, sh_in, sh_c, gam0_l0, gam1_l0, bet0_l0, bet1_l0,
              sh_redA, sh_redB, nullptr);

    float4 va = *(const float4*)&sh_in[lane * 8];
    float4 vb = *(const float4*)&sh_in[lane * 8 + 4];

    // phase B: gates1 = (wih1+whh1) @ h0 + bias1  (weights from LDS)
    {
      float accv[16];
#pragma unroll
      for (int r = 0; r < 16; ++r) {
        uint4 w = *(const uint4*)&sh_w1[wave * RPW + r][lane * 8];
        accv[r] = wave_sum(hdot8(w, va, vb));
      }
      float out = 0.f;
#pragma unroll
      for (int r = 0; r < 16; ++r) if (lane == r) out = accv[r];
      if (lane < RPW)
        __hip_atomic_store(&g1b[row0 + lane], out + bx,
                           __ATOMIC_RELAXED, __HIP_MEMORY_SCOPE_AGENT);
    }
    batch_barrier(flags, wgb, 2u * t + 2u);

    // layer-1 pointwise -> h into sh_h; leader WG writes y[b][t][:]
    float* ywr = (wgb == 0) ? (y + ((size_t)b * SS + t) * HH) : nullptr;
    pointwise(g1b, sh_h, sh_c, gam0_l1, gam1_l1, bet0_l1, bet1_l1,
              sh_redA, sh_redB, ywr);
  }
}

// ---------- launch ----------

extern "C" void kernel_launch(void* const* d_in, const int* in_sizes, int n_in,
                              void* d_out, int out_size, void* d_ws, size_t ws_size,
                              hipStream_t stream) {
  const float* x    = (const float*)d_in[0];
  const float* wih0 = (const float*)d_in[1];
  const float* whh0 = (const float*)d_in[2];
  const float* bih0 = (const float*)d_in[3];
  const float* bhh0 = (const float*)d_in[4];
  const float* wih1 = (const float*)d_in[5];
  const float* whh1 = (const float*)d_in[6];
  const float* bih1 = (const float*)d_in[7];
  const float* bhh1 = (const float*)d_in[8];
  const float* lnw  = (const float*)d_in[9];
  const float* lnb  = (const float*)d_in[10];
  float* y = (float*)d_out;

  char* ws = (char*)d_ws;
  const size_t WH = (size_t)BB * G4 * HH * 2;   // 33,554,432 B per fp16 matrix
  const size_t GX = (size_t)BB * SS * G4 * 4;   // 33,554,432 B g0x
  unsigned short* Wh0h = (unsigned short*)(ws);
  unsigned short* W1h  = (unsigned short*)(ws + WH);
  float* g0x   = (float*)(ws + 2 * WH);
  float* bias0 = (float*)(ws + 2 * WH + GX);
  float* bias1 = (float*)(ws + 2 * WH + GX + 131072);
  float* g0    = (float*)(ws + 2 * WH + GX + 2 * 131072);
  float* g1    = (float*)(ws + 2 * WH + GX + 3 * 131072);
  unsigned* bar = (unsigned*)(ws + 2 * WH + GX + 4 * 131072);  // 16*4KB = 64 KB flags

  hipLaunchKernelGGL(prep_kernel, dim3(4096), dim3(BLOCK), 0, stream,
                     whh0, wih1, whh1, bih0, bhh0, bih1, bhh1,
                     Wh0h, W1h, bias0, bias1, bar);

  hipLaunchKernelGGL(prep2_gemm, dim3(BB * 32), dim3(256), 0, stream,
                     wih0, x, bias0, g0x);

  void* args[] = { (void*)&Wh0h, (void*)&W1h, (void*)&g0x,
                   (void*)&bias1, (void*)&lnw, (void*)&lnb,
                   (void*)&g0, (void*)&g1, (void*)&bar, (void*)&y };
  hipError_t err = hipLaunchCooperativeKernel(reinterpret_cast<const void*>(&lstm_main),
                                              dim3(GRID), dim3(BLOCK), args, 0, stream);
  if (err != hipSuccess) {
    // fallback: plain launch — grid sized to guaranteed co-residency (2 blocks/CU)
    hipLaunchKernelGGL(lstm_main, dim3(GRID), dim3(BLOCK), 0, stream,
                       Wh0h, W1h, g0x, bias1, lnw, lnb, g0, g1, bar, y);
  }
}